// Round 4
// baseline (1253.875 us; speedup 1.0000x reference)
//
#include <hip/hip_runtime.h>

typedef unsigned short u16;
typedef unsigned int u32;

#define VV 50257
#define NCAND 509
#define NFWD 48
#define NRETRO 16

typedef __attribute__((ext_vector_type(8))) short bf16x8;
typedef __attribute__((ext_vector_type(4))) float f32x4;

__device__ __forceinline__ float bf2f(u16 u) {
  union { u32 i; float f; } v; v.i = ((u32)u) << 16; return v.f;
}
__device__ __forceinline__ u16 f2bf(float f) {
  union { float f; u32 u; } v; v.f = f;
  u32 u = v.u; u += 0x7fffu + ((u >> 16) & 1u); return (u16)(u >> 16);
}
// truncating bf16 (hi part of a hi/lo split; lo = v - bf2f(hi) then RNE)
__device__ __forceinline__ u16 bft(float f) {
  union { float f; u32 u; } v; v.f = f; return (u16)(v.u >> 16);
}
__device__ __forceinline__ float ldsel(const void* p, size_t i, int isbf) {
  return isbf ? bf2f(((const u16*)p)[i]) : ((const float*)p)[i];
}

// async global->LDS, 16B per lane; LDS dest = base + lane*16 (wave-uniform base)
__device__ __forceinline__ void g2l16(const u16* g, u16* l) {
  __builtin_amdgcn_global_load_lds((const __attribute__((address_space(1))) u32*)g,
                                   (__attribute__((address_space(3))) u32*)l, 16, 0, 0);
}

// dtype detector (kept for ldsel-based small kernels; runtime shows fp32)
__global__ void detect_k(const u32* __restrict__ w, int* __restrict__ flag) {
  int bf = 1;
  for (int i = 0; i < 16; ++i) {
    u32 b1 = (w[i] >> 8) & 0x7fu;
    if (!(b1 >= 0x30u && b1 < 0x40u)) bf = 0;
  }
  *flag = bf;
}

__global__ void sentinel_k(float* __restrict__ out, int n, float val) {
  int i = blockIdx.x * 256 + threadIdx.x;
  if (i < n) out[i] = val;
}

// ---------------------------------------------------------------------------
// Weight transform: W[K][N] fp32 -> hi/lo bf16 planes T[N][K], XOR-swizzled
// within each 64-elem k-block: k' = (k&~63) | ((k&63) ^ ((n&7)<<3)).
// ---------------------------------------------------------------------------
__global__ __launch_bounds__(256) void tsplit_k(const float* __restrict__ W,
                                                u16* __restrict__ Th, u16* __restrict__ Tl,
                                                int K, int N) {
  __shared__ float tt[32][33];
  int nt = N >> 5;
  int n0 = (blockIdx.x % nt) << 5;
  int k0 = (blockIdx.x / nt) << 5;
  int c = threadIdx.x & 31, r = threadIdx.x >> 5;   // r in 0..7
#pragma unroll
  for (int i = 0; i < 32; i += 8) tt[r + i][c] = W[(size_t)(k0 + r + i) * N + n0 + c];
  __syncthreads();
#pragma unroll
  for (int i = 0; i < 32; i += 8) {
    int n = n0 + r + i, k = k0 + c;
    float v = tt[c][r + i];
    u16 h = bft(v);
    int idx = n * K + (k & ~63) + ((k & 63) ^ ((n & 7) << 3));
    Th[idx] = h; Tl[idx] = f2bf(v - bf2f(h));
  }
}

// gathered embed rows -> swizzled hi/lo planes (chunk of 16384 rows)
__global__ __launch_bounds__(256) void gsplit_k(const float* __restrict__ embed,
                                                const int* __restrict__ seqp,
                                                u16* __restrict__ Ph, u16* __restrict__ Pl) {
  int g = blockIdx.x * 256 + threadIdx.x;   // over 16384*64
  int m = g >> 6, j8 = (g & 63) << 3;
  const float* s = embed + (size_t)seqp[m] * 512 + j8;
  float4 a = *(const float4*)s;
  float4 b = *(const float4*)(s + 4);
  u16 h0 = bft(a.x), h1 = bft(a.y), h2 = bft(a.z), h3 = bft(a.w);
  u16 h4 = bft(b.x), h5 = bft(b.y), h6 = bft(b.z), h7 = bft(b.w);
  uint4 hv, lv;
  hv.x = (u32)h0 | ((u32)h1 << 16); hv.y = (u32)h2 | ((u32)h3 << 16);
  hv.z = (u32)h4 | ((u32)h5 << 16); hv.w = (u32)h6 | ((u32)h7 << 16);
  lv.x = (u32)f2bf(a.x - bf2f(h0)) | ((u32)f2bf(a.y - bf2f(h1)) << 16);
  lv.y = (u32)f2bf(a.z - bf2f(h2)) | ((u32)f2bf(a.w - bf2f(h3)) << 16);
  lv.z = (u32)f2bf(b.x - bf2f(h4)) | ((u32)f2bf(b.y - bf2f(h5)) << 16);
  lv.w = (u32)f2bf(b.z - bf2f(h6)) | ((u32)f2bf(b.w - bf2f(h7)) << 16);
  int di = m * 512 + (j8 ^ ((m & 7) << 3));
  *(uint4*)&Ph[di] = hv;
  *(uint4*)&Pl[di] = lv;
}

// ---------------------------------------------------------------------------
// 3-pass split-bf16 MFMA GEMM: C[M,512] = epi(A @ B), K=512.
// C ~= Ah.Bh + Al.Bh + Ah.Bl  (AlBl ~2^-16 dropped).
// 128x128 tile, 4 waves 2x2, mfma_f32_16x16x32_bf16, global_load_lds staging.
// ADDM: 1 = + residual planes (hi+lo) at [m][n];  2 = + addf[(m>>9)*512+n]
// OUT : 0 fp32 C[m][n]; 1 bf16 C[m][n]; 2 swizzled hi/lo planes;
//       3 fp32 with row remap m -> (m/48)*64 + m%48 (memory[0:48] slots)
// ---------------------------------------------------------------------------
template<int ADDM, int RELU, int ACC, int OUT>
__global__ __launch_bounds__(256) void mgemm_k(
    const u16* __restrict__ Ah, const u16* __restrict__ Al,
    const u16* __restrict__ Bh, const u16* __restrict__ Bl,
    int ldk, int koff,
    const float* __restrict__ biasf, int boff,
    const u16* __restrict__ Rh, const u16* __restrict__ Rl,
    const float* __restrict__ addf,
    float* __restrict__ Cf, u16* __restrict__ Cb,
    u16* __restrict__ Ohi, u16* __restrict__ Olo)
{
  __shared__ __align__(16) u16 lds[32768];   // 4 planes x 128x64 u16 (64 KB)
  int tid = threadIdx.x;
  int cpx = gridDim.x >> 3;                  // XCD-chunked swizzle (grid % 8 == 0)
  int bid = blockIdx.x;
  int wg = (bid & 7) * cpx + (bid >> 3);
  int my = wg >> 2, nx = wg & 3;
  int m0 = my << 7, n0 = nx << 7;
  int lane = tid & 63, wid = tid >> 6;

  // staging: wave w stages plane w (0=Ah,1=Al,2=Bh,3=Bl)
  const u16* gw; int stw;
  if (wid == 0)      { gw = Ah + (size_t)m0 * 512;        stw = 512; }
  else if (wid == 1) { gw = Al + (size_t)m0 * 512;        stw = 512; }
  else if (wid == 2) { gw = Bh + (size_t)n0 * ldk + koff; stw = ldk; }
  else               { gw = Bl + (size_t)n0 * ldk + koff; stw = ldk; }
  const u16* gl = gw + (size_t)(lane >> 3) * stw + ((lane & 7) << 3);
  int lb = wid << 13;

  f32x4 acc[4][4] = {};
  int wr = wid >> 1, wc = wid & 1;
  int cl = lane & 15;
  int kq8 = (lane >> 4) << 3;
  int swz = (cl & 7) << 3;

  for (int k0 = 0; k0 < 512; k0 += 64) {
#pragma unroll
    for (int i = 0; i < 16; ++i)
      g2l16(gl + (size_t)(i << 3) * stw + k0, &lds[lb + (i << 9)]);
    __syncthreads();
#pragma unroll
    for (int kt = 0; kt < 2; ++kt) {
      int kA = ((kt << 5) + kq8) ^ swz;
      bf16x8 bh[4], blo[4];
#pragma unroll
      for (int i = 0; i < 4; ++i) {
        int ib = (((wc << 6) + (i << 4) + cl) << 6) + kA;
        bh[i]  = *(const bf16x8*)&lds[16384 + ib];
        blo[i] = *(const bf16x8*)&lds[24576 + ib];
      }
#pragma unroll
      for (int i2 = 0; i2 < 4; ++i2) {
        int ia = (((wr << 6) + (i2 << 4) + cl) << 6) + kA;
        bf16x8 ah  = *(const bf16x8*)&lds[ia];
        bf16x8 alo = *(const bf16x8*)&lds[8192 + ia];
#pragma unroll
        for (int j = 0; j < 4; ++j) {
          acc[i2][j] = __builtin_amdgcn_mfma_f32_16x16x32_bf16(ah,  bh[j],  acc[i2][j], 0, 0, 0);
          acc[i2][j] = __builtin_amdgcn_mfma_f32_16x16x32_bf16(alo, bh[j],  acc[i2][j], 0, 0, 0);
          acc[i2][j] = __builtin_amdgcn_mfma_f32_16x16x32_bf16(ah,  blo[j], acc[i2][j], 0, 0, 0);
        }
      }
    }
    __syncthreads();
  }

  // C/D layout: col = lane&15, row = (lane>>4)*4 + reg  [m89/m91]
  int rq = (lane >> 4) << 2;
  int mb = m0 + (wr << 6);
  int nb = n0 + (wc << 6);
#pragma unroll
  for (int j = 0; j < 4; ++j) {
    int n = nb + (j << 4) + cl;
    float bi = biasf ? biasf[boff + n] : 0.f;
#pragma unroll
    for (int i2 = 0; i2 < 4; ++i2) {
#pragma unroll
      for (int r = 0; r < 4; ++r) {
        int m = mb + (i2 << 4) + rq + r;
        float v = acc[i2][j][r] + bi;
        if (ADDM == 1) {
          int ridx = m * 512 + (n ^ ((m & 7) << 3));
          v += bf2f(Rh[ridx]) + bf2f(Rl[ridx]);
        }
        if (ADDM == 2) v += addf[((m >> 9) << 9) + n];
        if (ACC) v += Cf[(size_t)m * 512 + n];
        if (RELU) v = fmaxf(v, 0.f);
        if (OUT == 0) Cf[(size_t)m * 512 + n] = v;
        else if (OUT == 1) Cb[(size_t)m * 512 + n] = f2bf(v);
        else if (OUT == 2) {
          u16 h = bft(v);
          int oidx = m * 512 + (n ^ ((m & 7) << 3));
          Ohi[oidx] = h; Olo[oidx] = f2bf(v - bf2f(h));
        } else {                       // OUT==3: memory[0:48] slots
          int r64 = (m * 43691) >> 21; // m/48 for m<3072
          int mm = (r64 << 6) + (m - r64 * 48);
          Cf[(size_t)mm * 512 + n] = v;
        }
      }
    }
  }
}

// ---------------------------------------------------------------------------
// old SIMT GEMM (kept only for the tiny gate_bias matmul, M=64)
// ---------------------------------------------------------------------------
template<int AG, int ADDM, int RELU, int ACC, int OUTBF>
__global__ __launch_bounds__(256) void gemm_k(
    const float* __restrict__ A, int lda,
    const void* __restrict__ gbase, const int* __restrict__ gidx,
    const void* __restrict__ Bw, int ldb, size_t boff,
    const void* __restrict__ bias, size_t bias_eoff,
    const void* __restrict__ adg_base, const int* __restrict__ adg_idx, int adg_ld,
    const float* __restrict__ addf, int add_shift, int addf_ld,
    void* __restrict__ Cv, int ldc, int K,
    const int* __restrict__ flagp)
{
  __shared__ float As[16][68];
  __shared__ float Bs[16][68];
  int isbf = *flagp;
  int tid = threadIdx.x;
  int m0 = blockIdx.y * 64;
  int n0 = blockIdx.x * 64;
  int tx = tid & 15, ty = tid >> 4;
  int arow = tid >> 2;
  int akq  = (tid & 3) << 2;
  int bcol = tid & 63;
  int bk0  = tid >> 6;

  size_t a_off;
  if (AG) a_off = (size_t)gidx[m0 + arow] * (size_t)lda;
  else    a_off = (size_t)(m0 + arow) * (size_t)lda;

  float acc[4][4] = {};

  for (int k0 = 0; k0 < K; k0 += 16) {
    {
      float4 v = *(const float4*)(A + a_off + k0 + akq);
      As[akq + 0][arow] = v.x;
      As[akq + 1][arow] = v.y;
      As[akq + 2][arow] = v.z;
      As[akq + 3][arow] = v.w;
    }
    if (isbf) {
      const u16* bp = (const u16*)Bw + boff;
#pragma unroll
      for (int l = 0; l < 4; ++l) {
        int kb = bk0 + (l << 2);
        Bs[kb][bcol] = bf2f(bp[(size_t)(k0 + kb) * ldb + n0 + bcol]);
      }
    } else {
      const float* bp = (const float*)Bw + boff;
#pragma unroll
      for (int l = 0; l < 4; ++l) {
        int kb = bk0 + (l << 2);
        Bs[kb][bcol] = bp[(size_t)(k0 + kb) * ldb + n0 + bcol];
      }
    }
    __syncthreads();
#pragma unroll
    for (int k = 0; k < 16; ++k) {
      float4 a4 = *(const float4*)&As[k][ty << 2];
      float4 b4 = *(const float4*)&Bs[k][tx << 2];
      float a[4] = {a4.x, a4.y, a4.z, a4.w};
      float bv[4] = {b4.x, b4.y, b4.z, b4.w};
#pragma unroll
      for (int i = 0; i < 4; ++i)
#pragma unroll
        for (int j = 0; j < 4; ++j) acc[i][j] += a[i] * bv[j];
    }
    __syncthreads();
  }

  int mrow = m0 + (ty << 2);
  int ncol = n0 + (tx << 2);
  float bi4[4] = {0.f, 0.f, 0.f, 0.f};
  if (bias) {
#pragma unroll
    for (int j = 0; j < 4; ++j) bi4[j] = ldsel(bias, bias_eoff + ncol + j, isbf);
  }
#pragma unroll
  for (int i = 0; i < 4; ++i) {
    int m = mrow + i;
    float v[4];
#pragma unroll
    for (int j = 0; j < 4; ++j) v[j] = acc[i][j] + bi4[j];
    if (RELU) {
#pragma unroll
      for (int j = 0; j < 4; ++j) v[j] = fmaxf(v[j], 0.f);
    }
    float4 o; o.x = v[0]; o.y = v[1]; o.z = v[2]; o.w = v[3];
    *(float4*)((float*)Cv + (size_t)m * ldc + ncol) = o;
  }
}

// LayerNorm: fp32 in -> swizzled hi/lo planes out
__global__ __launch_bounds__(256) void ln_split_k(const float* __restrict__ x,
                                                  const float* __restrict__ g,
                                                  const float* __restrict__ bt,
                                                  u16* __restrict__ Hh, u16* __restrict__ Hl) {
  int row = blockIdx.x;
  const float* p = x + (size_t)row * 512;
  int tid = threadIdx.x;
  __shared__ float red[256];
  __shared__ float stat[2];
  float v0 = p[tid], v1 = p[tid + 256];
  red[tid] = v0 + v1;
  __syncthreads();
  for (int s = 128; s > 0; s >>= 1) { if (tid < s) red[tid] += red[tid + s]; __syncthreads(); }
  if (tid == 0) stat[0] = red[0] * (1.0f / 512.0f);
  __syncthreads();
  float mu = stat[0];
  float d0 = v0 - mu, d1 = v1 - mu;
  red[tid] = d0 * d0 + d1 * d1;
  __syncthreads();
  for (int s = 128; s > 0; s >>= 1) { if (tid < s) red[tid] += red[tid + s]; __syncthreads(); }
  if (tid == 0) stat[1] = 1.0f / sqrtf(red[0] * (1.0f / 512.0f) + 1e-5f);
  __syncthreads();
  float inv = stat[1];
  float y0 = d0 * inv * g[tid] + bt[tid];
  float y1 = d1 * inv * g[tid + 256] + bt[tid + 256];
  int c = (row & 7) << 3;
  int i0 = row * 512 + (tid ^ c);
  int i1 = row * 512 + ((tid + 256) ^ c);
  u16 h0 = bft(y0), h1 = bft(y1);
  Hh[i0] = h0; Hl[i0] = f2bf(y0 - bf2f(h0));
  Hh[i1] = h1; Hl[i1] = f2bf(y1 - bf2f(h1));
}

// FUSED: fwd gate scores + context partial sums -- one pass over H planes
// (replaces score_p_k + context_part_p, each of which streamed all 64 MB)
__global__ __launch_bounds__(256) void gatectx_k(const u16* __restrict__ Hh,
                                                 const u16* __restrict__ Hl,
                                                 const float* __restrict__ w,
                                                 const float* __restrict__ b,
                                                 float* __restrict__ out,
                                                 float* __restrict__ part) {
  int bb = blockIdx.y, t0 = blockIdx.x * 64;
  __shared__ float wl[512];
  __shared__ float cred[4][512];
  for (int d = threadIdx.x; d < 512; d += 256) wl[d] = w[d];
  int wave = threadIdx.x >> 6, lane = threadIdx.x & 63;
  float ca[8] = {};
  __syncthreads();
  float bias = b[0];
  for (int r = wave; r < 64; r += 4) {
    int grow = bb * 512 + t0 + r;
    int lx = lane ^ ((grow & 7) << 3);
    const u16* ph = Hh + (size_t)grow * 512;
    const u16* pl = Hl + (size_t)grow * 512;
    float s = 0.f;
#pragma unroll
    for (int d = 0; d < 8; ++d) {
      float hv = bf2f(ph[lx + d * 64]) + bf2f(pl[lx + d * 64]);
      ca[d] += hv;
      s += hv * wl[lane + d * 64];
    }
#pragma unroll
    for (int off = 32; off > 0; off >>= 1) s += __shfl_xor(s, off);
    if (lane == 0) out[bb * 512 + t0 + r] = s + bias;
  }
#pragma unroll
  for (int d = 0; d < 8; ++d) cred[wave][lane + d * 64] = ca[d];
  __syncthreads();
  for (int d = threadIdx.x; d < 512; d += 256)
    part[(size_t)((bb << 3) + blockIdx.x) * 512 + d] =
        cred[0][d] + cred[1][d] + cred[2][d] + cred[3][d];
}

// gs = sigmoid(g1 @ nw_w2 + nw_b2), g1 fp32
template<int SIG>
__global__ __launch_bounds__(256) void score_k(const float* __restrict__ h,
                                               const void* __restrict__ w,
                                               const void* __restrict__ b,
                                               float* __restrict__ out,
                                               const int* __restrict__ flagp) {
  int isbf = *flagp;
  int bb = blockIdx.y; int t0 = blockIdx.x * 64;
  __shared__ float wl[512];
  for (int d = threadIdx.x; d < 512; d += 256) wl[d] = ldsel(w, d, isbf);
  __syncthreads();
  int wave = threadIdx.x >> 6, lane = threadIdx.x & 63;
  float bias = ldsel(b, 0, isbf);
  for (int r = wave; r < 64; r += 4) {
    const float* hp = h + ((size_t)bb * 512 + t0 + r) * 512;
    float s = 0.f;
#pragma unroll
    for (int d = 0; d < 8; ++d) s += hp[lane + d * 64] * wl[lane + d * 64];
#pragma unroll
    for (int off = 32; off > 0; off >>= 1) s += __shfl_xor(s, off);
    if (lane == 0) {
      float v = s + bias;
      if (SIG) v = 1.0f / (1.0f + expf(-v));
      out[bb * 512 + t0 + r] = v;
    }
  }
}

__global__ __launch_bounds__(256) void topk_fwd_k(const float* __restrict__ scores,
                                                  int* __restrict__ fwd_idx,
                                                  int* __restrict__ fwd_mask) {
  int b = blockIdx.x, tid = threadIdx.x;
  __shared__ float vals[512];
  __shared__ float rv[256];
  __shared__ int   ri[256];
  __shared__ int   selb[NFWD];
  for (int t = tid; t < 512; t += 256) {
    vals[t] = (t < NCAND) ? scores[b * 512 + t] : -3.0e38f;
    fwd_mask[b * 512 + t] = 0;
  }
  __syncthreads();
  for (int it = 0; it < NFWD; ++it) {
    float bv = -3.0e38f; int bi = 0x7fffffff;
    for (int t = tid; t < 512; t += 256) {
      float v = vals[t];
      if (v > bv || (v == bv && t < bi)) { bv = v; bi = t; }
    }
    rv[tid] = bv; ri[tid] = bi;
    __syncthreads();
    for (int s = 128; s > 0; s >>= 1) {
      if (tid < s) {
        float ov = rv[tid + s]; int oi = ri[tid + s];
        if (ov > rv[tid] || (ov == rv[tid] && oi < ri[tid])) { rv[tid] = ov; ri[tid] = oi; }
      }
      __syncthreads();
    }
    if (tid == 0) { selb[it] = ri[0]; vals[ri[0]] = -3.0e38f; }
    __syncthreads();
  }
  if (tid == 0) {
    for (int i = 1; i < NFWD; ++i) {
      int v = selb[i], j = i - 1;
      while (j >= 0 && selb[j] > v) { selb[j + 1] = selb[j]; --j; }
      selb[j + 1] = v;
    }
    for (int i = 0; i < NFWD; ++i) {
      fwd_idx[b * NFWD + i] = selb[i];
      fwd_mask[b * 512 + selb[i]] = 1;
    }
  }
}

__global__ __launch_bounds__(256) void topk_retro_k(const float* __restrict__ gs,
                                                    const int* __restrict__ fwd_mask,
                                                    int* __restrict__ sel) {
  int b = blockIdx.x, tid = threadIdx.x;
  __shared__ float vals[512];
  __shared__ float rv[256];
  __shared__ int   ri[256];
  for (int t = tid; t < 512; t += 256) {
    float v;
    if (t < NCAND) v = fwd_mask[b * 512 + t] ? -1.0e9f : gs[b * 512 + t];
    else v = -3.0e38f;
    vals[t] = v;
  }
  __syncthreads();
  for (int it = 0; it < NRETRO; ++it) {
    float bv = -3.0e38f; int bi = 0x7fffffff;
    for (int t = tid; t < 512; t += 256) {
      float v = vals[t];
      if (v > bv || (v == bv && t < bi)) { bv = v; bi = t; }
    }
    rv[tid] = bv; ri[tid] = bi;
    __syncthreads();
    for (int s = 128; s > 0; s >>= 1) {
      if (tid < s) {
        float ov = rv[tid + s]; int oi = ri[tid + s];
        if (ov > rv[tid] || (ov == rv[tid] && oi < ri[tid])) { rv[tid] = ov; ri[tid] = oi; }
      }
      __syncthreads();
    }
    if (tid == 0) { sel[b * NRETRO + it] = ri[0]; vals[ri[0]] = -3.0e38f; }
    __syncthreads();
  }
}

__global__ __launch_bounds__(512) void context_red_k(const float* __restrict__ part,
                                                     float* __restrict__ ctx) {
  int b = blockIdx.x, d = threadIdx.x;
  float s = 0.f;
#pragma unroll
  for (int c = 0; c < 8; ++c) s += part[(size_t)((b << 3) + c) * 512 + d];
  ctx[b * 512 + d] = s * (1.0f / 512.0f);
}

// gather fwd rows -> planes (for q MFMA gemm)
__global__ __launch_bounds__(256) void fwdh_gather_p(const u16* __restrict__ Hh,
                                                     const u16* __restrict__ Hl,
                                                     const int* __restrict__ fwd_idx,
                                                     u16* __restrict__ Fh, u16* __restrict__ Fl) {
  int idx = blockIdx.x * 256 + threadIdx.x;   // 3072*512
  int d = idx & 511, r = idx >> 9;
  int b = r / NFWD, i = r % NFWD;
  int t = fwd_idx[b * NFWD + i];
  int srow = b * 512 + t;
  int si = srow * 512 + (d & ~63) + ((d & 63) ^ ((srow & 7) << 3));
  float v = bf2f(Hh[si]) + bf2f(Hl[si]);
  u16 h = bft(v);
  int di = r * 512 + (d & ~63) + ((d & 63) ^ ((r & 7) << 3));
  Fh[di] = h; Fl[di] = f2bf(v - bf2f(h));
}

// gather retro rows -> memory[48:64] fp32
__global__ __launch_bounds__(256) void retro_gather_p(const u16* __restrict__ Hh,
                                                      const u16* __restrict__ Hl,
                                                      const int* __restrict__ sel,
                                                      float* __restrict__ mem) {
  int idx = blockIdx.x * 256 + threadIdx.x;
  int d = idx & 511, r = idx >> 9, b = r >> 4, j = r & 15;
  int t = sel[b * NRETRO + j];
  int srow = b * 512 + t;
  int si = srow * 512 + (d & ~63) + ((d & 63) ^ ((srow & 7) << 3));
  mem[((size_t)b * 64 + NFWD + j) * 512 + d] = bf2f(Hh[si]) + bf2f(Hl[si]);
}

// S[b,k,t] = q.k / sqrt(512); kk bf16
__global__ __launch_bounds__(256) void s_k(const float* __restrict__ q,
                                           const u16* __restrict__ kk,
                                           float* __restrict__ S) {
  int b = blockIdx.y, t0 = blockIdx.x * 64;
  int tid = threadIdx.x, tq = tid & 15, kq = tid >> 4;
  __shared__ float qs[16][49];
  __shared__ float ks[16][68];
  float acc[3][4] = {};
  for (int dc = 0; dc < 512; dc += 16) {
    for (int e = tid; e < 768; e += 256) {
      int d = e / 48, k2 = e % 48;
      qs[d][k2] = q[((size_t)b * 48 + k2) * 512 + dc + d];
    }
    for (int e = tid; e < 1024; e += 256) {
      int t = e >> 4, d = e & 15;
      ks[d][t] = bf2f(kk[((size_t)b * 512 + t0 + t) * 512 + dc + d]);
    }
    __syncthreads();
#pragma unroll
    for (int d = 0; d < 16; ++d) {
      float4 kv = *(const float4*)&ks[d][tq << 2];
#pragma unroll
      for (int j = 0; j < 3; ++j) {
        float qv = qs[d][kq * 3 + j];
        acc[j][0] += qv * kv.x; acc[j][1] += qv * kv.y;
        acc[j][2] += qv * kv.z; acc[j][3] += qv * kv.w;
      }
    }
    __syncthreads();
  }
  const float sc = 0.044194173824159216f;
#pragma unroll
  for (int j = 0; j < 3; ++j) {
    int k = kq * 3 + j;
    float4 o; o.x = acc[j][0] * sc; o.y = acc[j][1] * sc;
    o.z = acc[j][2] * sc; o.w = acc[j][3] * sc;
    *(float4*)&S[((size_t)b * 48 + k) * 512 + t0 + (tq << 2)] = o;
  }
}

__global__ __launch_bounds__(256) void softmax_k(float* __restrict__ S) {
  float* p = S + (size_t)blockIdx.x * 512;
  int tid = threadIdx.x;
  __shared__ float red[256];
  __shared__ float stat[2];
  float v0 = p[tid], v1 = p[tid + 256];
  red[tid] = fmaxf(v0, v1);
  __syncthreads();
  for (int s = 128; s > 0; s >>= 1) { if (tid < s) red[tid] = fmaxf(red[tid], red[tid + s]); __syncthreads(); }
  if (tid == 0) stat[0] = red[0];
  __syncthreads();
  float mx = stat[0];
  float e0 = expf(v0 - mx), e1 = expf(v1 - mx);
  red[tid] = e0 + e1;
  __syncthreads();
  for (int s = 128; s > 0; s >>= 1) { if (tid < s) red[tid] += red[tid + s]; __syncthreads(); }
  if (tid == 0) stat[1] = 1.0f / red[0];
  __syncthreads();
  float inv = stat[1];
  p[tid] = e0 * inv; p[tid + 256] = e1 * inv;
}

// attn_out = P @ V; outputs swizzled hi/lo planes for the wo MFMA gemm
__global__ __launch_bounds__(256) void pv_k(const float* __restrict__ P,
                                            const u16* __restrict__ vvp,
                                            u16* __restrict__ Ph, u16* __restrict__ Pl) {
  int b = blockIdx.y, d0 = blockIdx.x * 64;
  int tid = threadIdx.x, dq = tid & 15, kq = tid >> 4;
  __shared__ float ps[16][49];
  __shared__ float vs[16][68];
  float acc[3][4] = {};
  for (int tc = 0; tc < 512; tc += 16) {
    for (int e = tid; e < 768; e += 256) {
      int t = e / 48, k2 = e % 48;
      ps[t][k2] = P[((size_t)b * 48 + k2) * 512 + tc + t];
    }
    for (int e = tid; e < 1024; e += 256) {
      int t = e >> 6, d = e & 63;
      vs[t][d] = bf2f(vvp[((size_t)b * 512 + tc + t) * 512 + d0 + d]);
    }
    __syncthreads();
#pragma unroll
    for (int t = 0; t < 16; ++t) {
      float4 vval = *(const float4*)&vs[t][dq << 2];
#pragma unroll
      for (int j = 0; j < 3; ++j) {
        float pp = ps[t][kq * 3 + j];
        acc[j][0] += pp * vval.x; acc[j][1] += pp * vval.y;
        acc[j][2] += pp * vval.z; acc[j][3] += pp * vval.w;
      }
    }
    __syncthreads();
  }
#pragma unroll
  for (int j = 0; j < 3; ++j) {
    int k = kq * 3 + j;
    int row = b * 48 + k;
    int c = (row & 7) << 3;
    int di = row * 512 + d0 + ((dq << 2) ^ c);
    float v0 = acc[j][0], v1 = acc[j][1], v2 = acc[j][2], v3 = acc[j][3];
    u16 h0 = bft(v0), h1 = bft(v1), h2 = bft(v2), h3 = bft(v3);
    uint2 hv, lv;
    hv.x = (u32)h0 | ((u32)h1 << 16); hv.y = (u32)h2 | ((u32)h3 << 16);
    lv.x = (u32)f2bf(v0 - bf2f(h0)) | ((u32)f2bf(v1 - bf2f(h1)) << 16);
    lv.y = (u32)f2bf(v2 - bf2f(h2)) | ((u32)f2bf(v3 - bf2f(h3)) << 16);
    *(uint2*)&Ph[di] = hv;
    *(uint2*)&Pl[di] = lv;
  }
}

__global__ __launch_bounds__(512) void qh_p_k(const u16* __restrict__ Hh,
                                              const u16* __restrict__ Hl,
                                              const float* __restrict__ rq_w,
                                              const float* __restrict__ rq_b,
                                              float* __restrict__ qh) {
  int b = blockIdx.x, d = threadIdx.x;
  __shared__ float hr[512];
  int row = b * 512 + 510;                       // (510&7)=6 -> key 48
  int idx = row * 512 + (d & ~63) + ((d & 63) ^ 48);
  hr[d] = bf2f(Hh[idx]) + bf2f(Hl[idx]);
  __syncthreads();
  float s = 0.f;
  for (int k = 0; k < 512; ++k) s += hr[k] * rq_w[(size_t)k * 512 + d];
  qh[b * 512 + d] = s + rq_b[d];
}

// mem softmax + ctx; emits ctxT for vocab GEMM scalar loads
__global__ __launch_bounds__(512) void mem_attn_k(const float* __restrict__ mem,
                                                  const float* __restrict__ qh,
                                                  float* __restrict__ ctx,
                                                  float* __restrict__ ctxT) {
  int b = blockIdx.x, tid = threadIdx.x;
  __shared__ float qv[512];
  __shared__ float sc[64];
  qv[tid] = qh[b * 512 + tid];
  __syncthreads();
  if (tid < 64) {
    const float* mp = mem + ((size_t)b * 64 + tid) * 512;
    float s = 0.f;
    for (int d = 0; d < 512; ++d) s += mp[d] * qv[d];
    float mx = s;
#pragma unroll
    for (int off = 32; off > 0; off >>= 1) mx = fmaxf(mx, __shfl_xor(mx, off));
    float e = expf(s - mx);
    float sum = e;
#pragma unroll
    for (int off = 32; off > 0; off >>= 1) sum += __shfl_xor(sum, off);
    sc[tid] = e / sum;
  }
  __syncthreads();
  float a = 0.f;
  for (int m = 0; m < 64; ++m) a += sc[m] * mem[((size_t)b * 64 + m) * 512 + tid];
  ctx[b * 512 + tid] = a;
  ctxT[(size_t)tid * 64 + b] = a;
}

// vocab projection, k-split x2 + batch-split x8 -> 3152 active blocks
// (old 788-block version was latency-bound: 30% occupancy, 26% VALUBusy).
// Partials P0/P1 go to the then-dead region-A workspace; combine adds bias.
__global__ __launch_bounds__(256) void out_part_k(const float* __restrict__ ctxT,
                                                  const float* __restrict__ out_w,
                                                  float* __restrict__ P0,
                                                  float* __restrict__ P1) {
  int bid = blockIdx.x;
  int slab2 = (bid & 7) + ((bid >> 6) << 3);   // 0..399; same bid&7 -> same XCD
  if (slab2 >= 394) return;                     // 3200-block launch, 3152 active
  int xslab = slab2 >> 1, kh = slab2 & 1;
  int bg = (bid >> 3) & 7;
  int n = xslab * 256 + threadIdx.x;
  int nc = n < VV ? n : VV - 1;
  int b0 = bg << 3;
  int k0 = kh << 8;
  float acc[8] = {};
  const float* wp = out_w + (size_t)k0 * VV;
#pragma unroll 8
  for (int k = 0; k < 256; ++k) {
    float w = wp[(size_t)k * VV + nc];
    const float* cp = ctxT + ((size_t)(k0 + k) << 6) + b0;   // uniform -> s_load
#pragma unroll
    for (int i = 0; i < 8; ++i) acc[i] += cp[i] * w;
  }
  float* dst = kh ? P1 : P0;
  if (n < VV) {
#pragma unroll
    for (int i = 0; i < 8; ++i) dst[(size_t)(b0 + i) * VV + n] = acc[i];
  }
}

__global__ __launch_bounds__(256) void out_comb_k(const float* __restrict__ P0,
                                                  const float* __restrict__ P1,
                                                  const float* __restrict__ ob,
                                                  float* __restrict__ out) {
  int b = blockIdx.y;
  int n = blockIdx.x * 256 + threadIdx.x;
  if (n < VV) {
    size_t i = (size_t)b * VV + n;
    out[i] = P0[i] + P1[i] + ob[n];
  }
}

extern "C" void kernel_launch(void* const* d_in, const int* in_sizes, int n_in,
                              void* d_out, int out_size, void* d_ws, size_t ws_size,
                              hipStream_t stream) {
  const int*  seq    = (const int*)d_in[0];
  const void* embed  = d_in[1];
  const void* ff_w1  = d_in[2];
  const void* ff_b1  = d_in[3];
  const void* ff_w2  = d_in[4];
  const void* ff_b2  = d_in[5];
  const void* ln_g   = d_in[6];
  const void* ln_b   = d_in[7];
  const void* fg_w   = d_in[8];
  const void* fg_b   = d_in[9];
  const void* nw_w1  = d_in[10];
  const void* nw_b1  = d_in[11];
  const void* nw_w2  = d_in[12];
  const void* nw_b2  = d_in[13];
  const void* wq     = d_in[14];
  const void* bq     = d_in[15];
  const void* wk     = d_in[16];
  const void* bk     = d_in[17];
  const void* wv     = d_in[18];
  const void* bv     = d_in[19];
  const void* wo     = d_in[20];
  const void* bo     = d_in[21];
  const void* rq_w   = d_in[22];
  const void* rq_b   = d_in[23];
  const void* out_w  = d_in[24];
  const void* out_b  = d_in[25];
  float* out = (float*)d_out;

  // ---- workspace (float units), NEED = 43,778,048 f
  float* ws = (float*)d_ws;
  // region A [0, 16,777,216): hidden fp32 -> g1 fp32 -> kku|vvu -> P0|P1
  float* hidden = ws;
  float* g1f    = ws;
  u16*   kku    = (u16*)ws;                     // 32768x512 u16
  u16*   vvu    = (u16*)(ws + 8388608);
  float* P0     = ws;                           // 64xVV fp32 partials (3,216,448 f)
  float* P1     = ws + 3216448;
  // region R [16,777,216, 33,554,432):
  u16* actHh = (u16*)(ws + 16777216);
  u16* actHl = actHh + 8388608;
  u16* h0h   = (u16*)(ws + 25165824);
  u16* h0l   = h0h + 8388608;
  u16* Hh    = (u16*)(ws + 16777216);           // 32768x512 planes (post-LN)
  u16* Hl    = Hh + 16777216;
  // region S1
  size_t S0 = 33554432;
  float* fwd_scores = ws + S0;
  float* gs         = ws + S0 + 32768;
  float* context    = ws + S0 + 65536;
  float* gate_bias  = ws + S0 + 98304;
  float* qh         = ws + S0 + 131072;
  float* ctx        = ws + S0 + 163840;
  int*   fwd_idx    = (int*)(ws + S0 + 196608);
  int*   sel        = (int*)(ws + S0 + 199680);
  int*   fwd_mask   = (int*)(ws + S0 + 200704);
  int*   flagp      = (int*)(ws + S0 + 233472);
  float* cpart      = ws + S0 + 262144;         // context partials (dies early)
  u16*   Fh         = (u16*)(ws + S0 + 262144); // fwd_h planes (after cpart dead)
  u16*   Fl         = Fh + 1572864;
  float* q          = ws + S0 + 1835008;
  float* Smat       = ws + S0 + 3407872;
  // weight planes pack (dies before s_k writes Smat / pv writes attn planes)
  u16* W0   = (u16*)(ws + S0 + 3407872);
  u16* WTnh = W0;            u16* WTnl = W0 + 262144;
  u16* WTkh = W0 + 524288;   u16* WTkl = W0 + 786432;
  u16* WTvh = W0 + 1048576;  u16* WTvl = W0 + 1310720;
  u16* WT1h = W0 + 1572864;  u16* WT1l = W0 + 2097152;   // 1024x512 each
  u16* WT2h = W0 + 2621440;  u16* WT2l = W0 + 3145728;   // 512x1024 each
  u16* Ph   = (u16*)(ws + S0 + 4980736);        // attn planes (pv out)
  u16* Pl   = Ph + 1572864;
  u16* Wq0  = (u16*)(ws + S0 + 6553600);
  u16* WTqh = Wq0;          u16* WTql = Wq0 + 262144;
  u16* WToh = Wq0 + 524288; u16* WTol = Wq0 + 786432;
  float* memory = ws + S0 + 8126464;
  float* ctxT   = fwd_scores;
  const size_t NEED = (size_t)(33554432 + 10223616) * 4;

  if (ws_size < NEED) {
    float val = 500.0f + (float)(ws_size >> 20);
    sentinel_k<<<(out_size + 255) / 256, 256, 0, stream>>>(out, out_size, val);
    return;
  }

  detect_k<<<1, 1, 0, stream>>>((const u32*)embed, flagp);

  // one-time weight transpose+split (swizzled bf16 planes)
  tsplit_k<<<512, 256, 0, stream>>>((const float*)ff_w1, WT1h, WT1l, 512, 1024);
  tsplit_k<<<512, 256, 0, stream>>>((const float*)ff_w2, WT2h, WT2l, 1024, 512);
  tsplit_k<<<256, 256, 0, stream>>>((const float*)nw_w1, WTnh, WTnl, 512, 512);
  tsplit_k<<<256, 256, 0, stream>>>((const float*)wk,    WTkh, WTkl, 512, 512);
  tsplit_k<<<256, 256, 0, stream>>>((const float*)wv,    WTvh, WTvl, 512, 512);
  tsplit_k<<<256, 256, 0, stream>>>((const float*)wq,    WTqh, WTql, 512, 512);
  tsplit_k<<<256, 256, 0, stream>>>((const float*)wo,    WToh, WTol, 512, 512);

  // FFN, M chunked x2 (planes fit workspace); two N/K halves per chunk
  for (int mc = 0; mc < 2; ++mc) {
    const int* seqp = seq + mc * 16384;
    float* hid = hidden + (size_t)mc * 16384 * 512;
    gsplit_k<<<4096, 256, 0, stream>>>((const float*)embed, seqp, h0h, h0l);
    mgemm_k<0,1,0,2><<<512, 256, 0, stream>>>(h0h, h0l, WT1h, WT1l, 512, 0,
        (const float*)ff_b1, 0, nullptr, nullptr, nullptr,
        nullptr, nullptr, actHh, actHl);
    mgemm_k<0,0,0,0><<<512, 256, 0, stream>>>(actHh, actHl, WT2h, WT2l, 1024, 0,
        nullptr, 0, nullptr, nullptr, nullptr,
        hid, nullptr, nullptr, nullptr);
    mgemm_k<0,1,0,2><<<512, 256, 0, stream>>>(h0h, h0l, WT1h + 512*512, WT1l + 512*512, 512, 0,
        (const float*)ff_b1, 512, nullptr, nullptr, nullptr,
        nullptr, nullptr, actHh, actHl);
    mgemm_k<1,0,1,0><<<512, 256, 0, stream>>>(actHh, actHl, WT2h, WT2l, 1024, 512,
        (const float*)ff_b2, 0, h0h, h0l, nullptr,
        hid, nullptr, nullptr, nullptr);
  }
  // LayerNorm -> H planes
  ln_split_k<<<32768, 256, 0, stream>>>(hidden, (const float*)ln_g, (const float*)ln_b, Hh, Hl);
  // FUSED fwd gate scores + context partials (one pass over H)
  gatectx_k<<<dim3(8,64), 256, 0, stream>>>(Hh, Hl, (const float*)fg_w, (const float*)fg_b,
                                            fwd_scores, cpart);
  topk_fwd_k<<<64, 256, 0, stream>>>(fwd_scores, fwd_idx, fwd_mask);
  context_red_k<<<64, 512, 0, stream>>>(cpart, context);
  // gate_bias = context @ nw_w1[512:,:] + nw_b1 (tiny, SIMT)
  gemm_k<0,0,0,0,0><<<dim3(8,1), 256, 0, stream>>>(
      context, 512, nullptr, nullptr, nw_w1, 512, (size_t)512*512, nw_b1, 0,
      nullptr, nullptr, 0, nullptr, 0, 0, gate_bias, 512, 512, flagp);
  // g1 = relu(H @ nw_w1[:512] + gate_bias)
  mgemm_k<2,1,0,0><<<1024, 256, 0, stream>>>(Hh, Hl, WTnh, WTnl, 512, 0,
      nullptr, 0, nullptr, nullptr, gate_bias,
      g1f, nullptr, nullptr, nullptr);
  score_k<1><<<dim3(8,64), 256, 0, stream>>>(g1f, nw_w2, nw_b2, gs, flagp);
  topk_retro_k<<<64, 256, 0, stream>>>(gs, fwd_mask, sel);
  retro_gather_p<<<2048, 256, 0, stream>>>(Hh, Hl, sel, memory);
  // q projection (MFMA, M=3072)
  fwdh_gather_p<<<6144, 256, 0, stream>>>(Hh, Hl, fwd_idx, Fh, Fl);
  mgemm_k<0,0,0,0><<<96, 256, 0, stream>>>(Fh, Fl, WTqh, WTql, 512, 0,
      (const float*)bq, 0, nullptr, nullptr, nullptr,
      q, nullptr, nullptr, nullptr);
  // K,V projections (bf16 out; overwrite dead g1 region)
  mgemm_k<0,0,0,1><<<1024, 256, 0, stream>>>(Hh, Hl, WTkh, WTkl, 512, 0,
      (const float*)bk, 0, nullptr, nullptr, nullptr,
      nullptr, kku, nullptr, nullptr);
  mgemm_k<0,0,0,1><<<1024, 256, 0, stream>>>(Hh, Hl, WTvh, WTvl, 512, 0,
      (const float*)bv, 0, nullptr, nullptr, nullptr,
      nullptr, vvu, nullptr, nullptr);
  // attention
  s_k<<<dim3(8,64), 256, 0, stream>>>(q, kku, Smat);
  softmax_k<<<3072, 256, 0, stream>>>(Smat);
  pv_k<<<dim3(8,64), 256, 0, stream>>>(Smat, vvu, Ph, Pl);
  // re_slots = attn @ wo + bo -> memory[0:48] directly (OUT=3 row remap)
  mgemm_k<0,0,0,3><<<96, 256, 0, stream>>>(Ph, Pl, WToh, WTol, 512, 0,
      (const float*)bo, 0, nullptr, nullptr, nullptr,
      memory, nullptr, nullptr, nullptr);
  // qh, memory softmax, vocab projection (split + combine)
  qh_p_k<<<64, 512, 0, stream>>>(Hh, Hl, (const float*)rq_w, (const float*)rq_b, qh);
  mem_attn_k<<<64, 512, 0, stream>>>(memory, qh, ctx, ctxT);
  out_part_k<<<3200, 256, 0, stream>>>(ctxT, (const float*)out_w, P0, P1);
  out_comb_k<<<dim3(197,64), 256, 0, stream>>>(P0, P1, (const float*)out_b, out);
}

// Round 5
// 1192.685 us; speedup vs baseline: 1.0513x; 1.0513x over previous
//
#include <hip/hip_runtime.h>

typedef unsigned short u16;
typedef unsigned int u32;

#define VV 50257
#define NCAND 509
#define NFWD 48
#define NRETRO 16

typedef __attribute__((ext_vector_type(8))) short bf16x8;
typedef __attribute__((ext_vector_type(4))) float f32x4;

__device__ __forceinline__ float bf2f(u16 u) {
  union { u32 i; float f; } v; v.i = ((u32)u) << 16; return v.f;
}
__device__ __forceinline__ u16 f2bf(float f) {
  union { float f; u32 u; } v; v.f = f;
  u32 u = v.u; u += 0x7fffu + ((u >> 16) & 1u); return (u16)(u >> 16);
}
// truncating bf16 (hi part of a hi/lo split; lo = v - bf2f(hi) then RNE)
__device__ __forceinline__ u16 bft(float f) {
  union { float f; u32 u; } v; v.f = f; return (u16)(v.u >> 16);
}
__device__ __forceinline__ float ldsel(const void* p, size_t i, int isbf) {
  return isbf ? bf2f(((const u16*)p)[i]) : ((const float*)p)[i];
}

// async global->LDS, 16B per lane; LDS dest = base + lane*16 (wave-uniform base)
__device__ __forceinline__ void g2l16(const u16* g, u16* l) {
  __builtin_amdgcn_global_load_lds((const __attribute__((address_space(1))) u32*)g,
                                   (__attribute__((address_space(3))) u32*)l, 16, 0, 0);
}

// dtype detector (for the SIMT gate_bias kernel; runtime shows fp32)
__global__ void detect_k(const u32* __restrict__ w, int* __restrict__ flag) {
  int bf = 1;
  for (int i = 0; i < 16; ++i) {
    u32 b1 = (w[i] >> 8) & 0x7fu;
    if (!(b1 >= 0x30u && b1 < 0x40u)) bf = 0;
  }
  *flag = bf;
}

__global__ void sentinel_k(float* __restrict__ out, int n, float val) {
  int i = blockIdx.x * 256 + threadIdx.x;
  if (i < n) out[i] = val;
}

// ---------------------------------------------------------------------------
// Weight transform: W[K][N] fp32 -> hi/lo bf16 planes T[N][K], XOR-swizzled
// within each 64-elem k-block: k' = (k&~63) | ((k&63) ^ ((n&7)<<3)).
// ---------------------------------------------------------------------------
__global__ __launch_bounds__(256) void tsplit_k(const float* __restrict__ W,
                                                u16* __restrict__ Th, u16* __restrict__ Tl,
                                                int K, int N) {
  __shared__ float tt[32][33];
  int nt = N >> 5;
  int n0 = (blockIdx.x % nt) << 5;
  int k0 = (blockIdx.x / nt) << 5;
  int c = threadIdx.x & 31, r = threadIdx.x >> 5;   // r in 0..7
#pragma unroll
  for (int i = 0; i < 32; i += 8) tt[r + i][c] = W[(size_t)(k0 + r + i) * N + n0 + c];
  __syncthreads();
#pragma unroll
  for (int i = 0; i < 32; i += 8) {
    int n = n0 + r + i, k = k0 + c;
    float v = tt[c][r + i];
    u16 h = bft(v);
    int idx = n * K + (k & ~63) + ((k & 63) ^ ((n & 7) << 3));
    Th[idx] = h; Tl[idx] = f2bf(v - bf2f(h));
  }
}

// out_w[512][VV] fp32 -> single-bf16 swizzled WoT[50304][512] (pad rows zeroed)
__global__ __launch_bounds__(256) void tout_k(const float* __restrict__ W,
                                              u16* __restrict__ WoT) {
  __shared__ float tt[32][33];
  const int nt = 1572;
  int n0 = (blockIdx.x % nt) << 5;
  int k0 = (blockIdx.x / nt) << 5;
  int c = threadIdx.x & 31, r = threadIdx.x >> 5;
#pragma unroll
  for (int i = 0; i < 32; i += 8) {
    int n = n0 + c;
    tt[r + i][c] = (n < VV) ? W[(size_t)(k0 + r + i) * VV + n] : 0.f;
  }
  __syncthreads();
#pragma unroll
  for (int i = 0; i < 32; i += 8) {
    int n = n0 + r + i, k = k0 + c;
    WoT[(size_t)n * 512 + (k & ~63) + ((k & 63) ^ ((n & 7) << 3))] = f2bf(tt[c][r + i]);
  }
}

// concat bias [bk | bv] -> bkv[1024]
__global__ void concat2_k(const float* __restrict__ a, const float* __restrict__ b,
                          float* __restrict__ o) {
  int i = blockIdx.x * 256 + threadIdx.x;
  if (i < 1024) o[i] = (i < 512) ? a[i] : b[i - 512];
}

// gathered embed rows -> swizzled hi/lo planes (chunk of 8192 rows)
__global__ __launch_bounds__(256) void gsplit_k(const float* __restrict__ embed,
                                                const int* __restrict__ seqp,
                                                u16* __restrict__ Ph, u16* __restrict__ Pl) {
  int g = blockIdx.x * 256 + threadIdx.x;   // over 8192*64
  int m = g >> 6, j8 = (g & 63) << 3;
  const float* s = embed + (size_t)seqp[m] * 512 + j8;
  float4 a = *(const float4*)s;
  float4 b = *(const float4*)(s + 4);
  u16 h0 = bft(a.x), h1 = bft(a.y), h2 = bft(a.z), h3 = bft(a.w);
  u16 h4 = bft(b.x), h5 = bft(b.y), h6 = bft(b.z), h7 = bft(b.w);
  uint4 hv, lv;
  hv.x = (u32)h0 | ((u32)h1 << 16); hv.y = (u32)h2 | ((u32)h3 << 16);
  hv.z = (u32)h4 | ((u32)h5 << 16); hv.w = (u32)h6 | ((u32)h7 << 16);
  lv.x = (u32)f2bf(a.x - bf2f(h0)) | ((u32)f2bf(a.y - bf2f(h1)) << 16);
  lv.y = (u32)f2bf(a.z - bf2f(h2)) | ((u32)f2bf(a.w - bf2f(h3)) << 16);
  lv.z = (u32)f2bf(b.x - bf2f(h4)) | ((u32)f2bf(b.y - bf2f(h5)) << 16);
  lv.w = (u32)f2bf(b.z - bf2f(h6)) | ((u32)f2bf(b.w - bf2f(h7)) << 16);
  int di = m * 512 + (j8 ^ ((m & 7) << 3));
  *(uint4*)&Ph[di] = hv;
  *(uint4*)&Pl[di] = lv;
}

// ---------------------------------------------------------------------------
// 3-pass split-bf16 MFMA GEMM (generalized): C[M, NT*128] = epi(A @ B).
// K = KST*64. A,B swizzled hi/lo bf16 planes; C ~= Ah.Bh + Al.Bh + Ah.Bl.
// 128x128 tile, 4 waves 2x2, mfma_f32_16x16x32_bf16, global_load_lds staging.
// ADDM: 1 = + residual planes (stride 512, n<512); 2 = + addf[(m>>9)*512+n]
// OUT : 0 fp32 Cf[m*ldc+n]; 1 bf16 Cb[m*ldc+n]; 2 swizzled hi/lo planes (ldc);
//       3 fp32 row remap m -> (m/48)*64 + m%48 (memory[0:48] slots)
// ---------------------------------------------------------------------------
template<int NT, int KST, int ADDM, int RELU, int OUT>
__global__ __launch_bounds__(256) void mgemm_k(
    const u16* __restrict__ Ah, const u16* __restrict__ Al,
    const u16* __restrict__ Bh, const u16* __restrict__ Bl,
    int lda, int ldb, int koff,
    const float* __restrict__ biasf, int boff,
    const u16* __restrict__ Rh, const u16* __restrict__ Rl,
    const float* __restrict__ addf,
    float* __restrict__ Cf, u16* __restrict__ Cb,
    u16* __restrict__ Ohi, u16* __restrict__ Olo, int ldc)
{
  __shared__ __align__(16) u16 lds[32768];   // 4 planes x 128x64 u16 (64 KB)
  int tid = threadIdx.x;
  int cpx = gridDim.x >> 3;                  // XCD-chunked swizzle (grid % 8 == 0)
  int bid = blockIdx.x;
  int wg = (bid & 7) * cpx + (bid >> 3);
  int my = wg / NT, nx = wg % NT;            // NT pow2 -> shifts
  int m0 = my << 7, n0 = nx << 7;
  int lane = tid & 63, wid = tid >> 6;

  // staging: wave w stages plane w (0=Ah,1=Al,2=Bh,3=Bl)
  const u16* gw; int stw;
  if (wid == 0)      { gw = Ah + (size_t)m0 * lda;        stw = lda; }
  else if (wid == 1) { gw = Al + (size_t)m0 * lda;        stw = lda; }
  else if (wid == 2) { gw = Bh + (size_t)n0 * ldb + koff; stw = ldb; }
  else               { gw = Bl + (size_t)n0 * ldb + koff; stw = ldb; }
  const u16* gl = gw + (size_t)(lane >> 3) * stw + ((lane & 7) << 3);
  int lb = wid << 13;

  f32x4 acc[4][4] = {};
  int wr = wid >> 1, wc = wid & 1;
  int cl = lane & 15;
  int kq8 = (lane >> 4) << 3;
  int swz = (cl & 7) << 3;

  for (int k0 = 0; k0 < KST * 64; k0 += 64) {
#pragma unroll
    for (int i = 0; i < 16; ++i)
      g2l16(gl + (size_t)(i << 3) * stw + k0, &lds[lb + (i << 9)]);
    __syncthreads();
#pragma unroll
    for (int kt = 0; kt < 2; ++kt) {
      int kA = ((kt << 5) + kq8) ^ swz;
      bf16x8 bh[4], blo[4];
#pragma unroll
      for (int i = 0; i < 4; ++i) {
        int ib = (((wc << 6) + (i << 4) + cl) << 6) + kA;
        bh[i]  = *(const bf16x8*)&lds[16384 + ib];
        blo[i] = *(const bf16x8*)&lds[24576 + ib];
      }
#pragma unroll
      for (int i2 = 0; i2 < 4; ++i2) {
        int ia = (((wr << 6) + (i2 << 4) + cl) << 6) + kA;
        bf16x8 ah  = *(const bf16x8*)&lds[ia];
        bf16x8 alo = *(const bf16x8*)&lds[8192 + ia];
#pragma unroll
        for (int j = 0; j < 4; ++j) {
          acc[i2][j] = __builtin_amdgcn_mfma_f32_16x16x32_bf16(ah,  bh[j],  acc[i2][j], 0, 0, 0);
          acc[i2][j] = __builtin_amdgcn_mfma_f32_16x16x32_bf16(alo, bh[j],  acc[i2][j], 0, 0, 0);
          acc[i2][j] = __builtin_amdgcn_mfma_f32_16x16x32_bf16(ah,  blo[j], acc[i2][j], 0, 0, 0);
        }
      }
    }
    __syncthreads();
  }

  // C/D layout: col = lane&15, row = (lane>>4)*4 + reg  [m89/m91]
  int rq = (lane >> 4) << 2;
  int mb = m0 + (wr << 6);
  int nb = n0 + (wc << 6);
#pragma unroll
  for (int j = 0; j < 4; ++j) {
    int n = nb + (j << 4) + cl;
    float bi = biasf ? biasf[boff + n] : 0.f;
#pragma unroll
    for (int i2 = 0; i2 < 4; ++i2) {
#pragma unroll
      for (int r = 0; r < 4; ++r) {
        int m = mb + (i2 << 4) + rq + r;
        float v = acc[i2][j][r] + bi;
        if (ADDM == 1) {
          int ridx = m * 512 + (n ^ ((m & 7) << 3));
          v += bf2f(Rh[ridx]) + bf2f(Rl[ridx]);
        }
        if (ADDM == 2) v += addf[((m >> 9) << 9) + n];
        if (RELU) v = fmaxf(v, 0.f);
        if (OUT == 0) Cf[(size_t)m * ldc + n] = v;
        else if (OUT == 1) Cb[(size_t)m * ldc + n] = f2bf(v);
        else if (OUT == 2) {
          u16 h = bft(v);
          size_t oidx = (size_t)m * ldc + (n & ~63) + ((n & 63) ^ ((m & 7) << 3));
          Ohi[oidx] = h; Olo[oidx] = f2bf(v - bf2f(h));
        } else {                       // OUT==3: memory[0:48] slots
          int r64 = (m * 43691) >> 21; // m/48 for m<3072
          int mm = (r64 << 6) + (m - r64 * 48);
          Cf[(size_t)mm * 512 + n] = v;
        }
      }
    }
  }
}

// ---------------------------------------------------------------------------
// Vocab MFMA GEMM: out[64][VV] = ctx(hi/lo planes) @ WoT(single bf16) + out_b.
// Tile 64m x 128n, 4 waves (each 64x32), 2 passes (Ah.B + Al.B).
// ---------------------------------------------------------------------------
__global__ __launch_bounds__(256) void out_mgemm_k(
    const u16* __restrict__ ctxh, const u16* __restrict__ ctxl,
    const u16* __restrict__ WoT, const float* __restrict__ ob,
    float* __restrict__ out) {
  __shared__ __align__(16) u16 lds[16384];   // Ah 4096 | Al 4096 | B 8192 (u16)
  int tid = threadIdx.x;
  int n0 = blockIdx.x << 7;
  int lane = tid & 63, wid = tid >> 6;
  const u16* gw; int lb0;
  if (wid == 0)      { gw = ctxh;                         lb0 = 0; }
  else if (wid == 1) { gw = ctxl;                         lb0 = 4096; }
  else if (wid == 2) { gw = WoT + (size_t)n0 * 512;        lb0 = 8192; }
  else               { gw = WoT + (size_t)(n0 + 64) * 512; lb0 = 12288; }
  const u16* gl = gw + (size_t)(lane >> 3) * 512 + ((lane & 7) << 3);

  f32x4 acc[4][2] = {};
  int cl = lane & 15;
  int kq8 = (lane >> 4) << 3;
  int swz = (cl & 7) << 3;

  for (int k0 = 0; k0 < 512; k0 += 64) {
#pragma unroll
    for (int i = 0; i < 8; ++i)
      g2l16(gl + (size_t)(i << 3) * 512 + k0, &lds[lb0 + (i << 9)]);
    __syncthreads();
#pragma unroll
    for (int kt = 0; kt < 2; ++kt) {
      int kA = ((kt << 5) + kq8) ^ swz;
      bf16x8 bw[2];
#pragma unroll
      for (int j = 0; j < 2; ++j) {
        int rB = (wid << 5) + (j << 4) + cl;
        bw[j] = *(const bf16x8*)&lds[8192 + (rB << 6) + kA];
      }
#pragma unroll
      for (int i2 = 0; i2 < 4; ++i2) {
        int ra = ((i2 << 4) + cl) << 6;
        bf16x8 ah  = *(const bf16x8*)&lds[ra + kA];
        bf16x8 alo = *(const bf16x8*)&lds[4096 + ra + kA];
#pragma unroll
        for (int j = 0; j < 2; ++j) {
          acc[i2][j] = __builtin_amdgcn_mfma_f32_16x16x32_bf16(ah,  bw[j], acc[i2][j], 0, 0, 0);
          acc[i2][j] = __builtin_amdgcn_mfma_f32_16x16x32_bf16(alo, bw[j], acc[i2][j], 0, 0, 0);
        }
      }
    }
    __syncthreads();
  }

  int rq = (lane >> 4) << 2;
#pragma unroll
  for (int j = 0; j < 2; ++j) {
    int n = n0 + (wid << 5) + (j << 4) + cl;
    if (n < VV) {
      float bi = ob[n];
#pragma unroll
      for (int i2 = 0; i2 < 4; ++i2)
#pragma unroll
        for (int r = 0; r < 4; ++r)
          out[(size_t)((i2 << 4) + rq + r) * VV + n] = acc[i2][j][r] + bi;
    }
  }
}

// ---------------------------------------------------------------------------
// SIMT GEMM (kept only for the tiny gate_bias matmul, M=64)
// ---------------------------------------------------------------------------
template<int AG, int ADDM, int RELU, int ACC, int OUTBF>
__global__ __launch_bounds__(256) void gemm_k(
    const float* __restrict__ A, int lda,
    const void* __restrict__ gbase, const int* __restrict__ gidx,
    const void* __restrict__ Bw, int ldb, size_t boff,
    const void* __restrict__ bias, size_t bias_eoff,
    const void* __restrict__ adg_base, const int* __restrict__ adg_idx, int adg_ld,
    const float* __restrict__ addf, int add_shift, int addf_ld,
    void* __restrict__ Cv, int ldc, int K,
    const int* __restrict__ flagp)
{
  __shared__ float As[16][68];
  __shared__ float Bs[16][68];
  int isbf = *flagp;
  int tid = threadIdx.x;
  int m0 = blockIdx.y * 64;
  int n0 = blockIdx.x * 64;
  int tx = tid & 15, ty = tid >> 4;
  int arow = tid >> 2;
  int akq  = (tid & 3) << 2;
  int bcol = tid & 63;
  int bk0  = tid >> 6;

  size_t a_off = (size_t)(m0 + arow) * (size_t)lda;
  float acc[4][4] = {};

  for (int k0 = 0; k0 < K; k0 += 16) {
    {
      float4 v = *(const float4*)(A + a_off + k0 + akq);
      As[akq + 0][arow] = v.x;
      As[akq + 1][arow] = v.y;
      As[akq + 2][arow] = v.z;
      As[akq + 3][arow] = v.w;
    }
    if (isbf) {
      const u16* bp = (const u16*)Bw + boff;
#pragma unroll
      for (int l = 0; l < 4; ++l) {
        int kb = bk0 + (l << 2);
        Bs[kb][bcol] = bf2f(bp[(size_t)(k0 + kb) * ldb + n0 + bcol]);
      }
    } else {
      const float* bp = (const float*)Bw + boff;
#pragma unroll
      for (int l = 0; l < 4; ++l) {
        int kb = bk0 + (l << 2);
        Bs[kb][bcol] = bp[(size_t)(k0 + kb) * ldb + n0 + bcol];
      }
    }
    __syncthreads();
#pragma unroll
    for (int k = 0; k < 16; ++k) {
      float4 a4 = *(const float4*)&As[k][ty << 2];
      float4 b4 = *(const float4*)&Bs[k][tx << 2];
      float a[4] = {a4.x, a4.y, a4.z, a4.w};
      float bv[4] = {b4.x, b4.y, b4.z, b4.w};
#pragma unroll
      for (int i = 0; i < 4; ++i)
#pragma unroll
        for (int j = 0; j < 4; ++j) acc[i][j] += a[i] * bv[j];
    }
    __syncthreads();
  }

  int mrow = m0 + (ty << 2);
  int ncol = n0 + (tx << 2);
  float bi4[4] = {0.f, 0.f, 0.f, 0.f};
  if (bias) {
#pragma unroll
    for (int j = 0; j < 4; ++j) bi4[j] = ldsel(bias, bias_eoff + ncol + j, isbf);
  }
#pragma unroll
  for (int i = 0; i < 4; ++i) {
    int m = mrow + i;
    float v[4];
#pragma unroll
    for (int j = 0; j < 4; ++j) v[j] = acc[i][j] + bi4[j];
    if (RELU) {
#pragma unroll
      for (int j = 0; j < 4; ++j) v[j] = fmaxf(v[j], 0.f);
    }
    float4 o; o.x = v[0]; o.y = v[1]; o.z = v[2]; o.w = v[3];
    *(float4*)((float*)Cv + (size_t)m * ldc + ncol) = o;
  }
}

// LayerNorm: fp32 in -> swizzled hi/lo planes out
__global__ __launch_bounds__(256) void ln_split_k(const float* __restrict__ x,
                                                  const float* __restrict__ g,
                                                  const float* __restrict__ bt,
                                                  u16* __restrict__ Hh, u16* __restrict__ Hl) {
  int row = blockIdx.x;
  const float* p = x + (size_t)row * 512;
  int tid = threadIdx.x;
  __shared__ float red[256];
  __shared__ float stat[2];
  float v0 = p[tid], v1 = p[tid + 256];
  red[tid] = v0 + v1;
  __syncthreads();
  for (int s = 128; s > 0; s >>= 1) { if (tid < s) red[tid] += red[tid + s]; __syncthreads(); }
  if (tid == 0) stat[0] = red[0] * (1.0f / 512.0f);
  __syncthreads();
  float mu = stat[0];
  float d0 = v0 - mu, d1 = v1 - mu;
  red[tid] = d0 * d0 + d1 * d1;
  __syncthreads();
  for (int s = 128; s > 0; s >>= 1) { if (tid < s) red[tid] += red[tid + s]; __syncthreads(); }
  if (tid == 0) stat[1] = 1.0f / sqrtf(red[0] * (1.0f / 512.0f) + 1e-5f);
  __syncthreads();
  float inv = stat[1];
  float y0 = d0 * inv * g[tid] + bt[tid];
  float y1 = d1 * inv * g[tid + 256] + bt[tid + 256];
  int c = (row & 7) << 3;
  int i0 = row * 512 + (tid ^ c);
  int i1 = row * 512 + ((tid + 256) ^ c);
  u16 h0 = bft(y0), h1 = bft(y1);
  Hh[i0] = h0; Hl[i0] = f2bf(y0 - bf2f(h0));
  Hh[i1] = h1; Hl[i1] = f2bf(y1 - bf2f(h1));
}

// FUSED: fwd gate scores + context partial sums (one pass over H planes)
__global__ __launch_bounds__(256) void gatectx_k(const u16* __restrict__ Hh,
                                                 const u16* __restrict__ Hl,
                                                 const float* __restrict__ w,
                                                 const float* __restrict__ b,
                                                 float* __restrict__ out,
                                                 float* __restrict__ part) {
  int bb = blockIdx.y, t0 = blockIdx.x * 64;
  __shared__ float wl[512];
  __shared__ float cred[4][512];
  for (int d = threadIdx.x; d < 512; d += 256) wl[d] = w[d];
  int wave = threadIdx.x >> 6, lane = threadIdx.x & 63;
  float ca[8] = {};
  __syncthreads();
  float bias = b[0];
  for (int r = wave; r < 64; r += 4) {
    int grow = bb * 512 + t0 + r;
    int lx = lane ^ ((grow & 7) << 3);
    const u16* ph = Hh + (size_t)grow * 512;
    const u16* pl = Hl + (size_t)grow * 512;
    float s = 0.f;
#pragma unroll
    for (int d = 0; d < 8; ++d) {
      float hv = bf2f(ph[lx + d * 64]) + bf2f(pl[lx + d * 64]);
      ca[d] += hv;
      s += hv * wl[lane + d * 64];
    }
#pragma unroll
    for (int off = 32; off > 0; off >>= 1) s += __shfl_xor(s, off);
    if (lane == 0) out[bb * 512 + t0 + r] = s + bias;
  }
#pragma unroll
  for (int d = 0; d < 8; ++d) cred[wave][lane + d * 64] = ca[d];
  __syncthreads();
  for (int d = threadIdx.x; d < 512; d += 256)
    part[(size_t)((bb << 3) + blockIdx.x) * 512 + d] =
        cred[0][d] + cred[1][d] + cred[2][d] + cred[3][d];
}

// gs = sigmoid(g1 @ nw_w2 + nw_b2), g1 fp32
template<int SIG>
__global__ __launch_bounds__(256) void score_k(const float* __restrict__ h,
                                               const void* __restrict__ w,
                                               const void* __restrict__ b,
                                               float* __restrict__ out,
                                               const int* __restrict__ flagp) {
  int isbf = *flagp;
  int bb = blockIdx.y; int t0 = blockIdx.x * 64;
  __shared__ float wl[512];
  for (int d = threadIdx.x; d < 512; d += 256) wl[d] = ldsel(w, d, isbf);
  __syncthreads();
  int wave = threadIdx.x >> 6, lane = threadIdx.x & 63;
  float bias = ldsel(b, 0, isbf);
  for (int r = wave; r < 64; r += 4) {
    const float* hp = h + ((size_t)bb * 512 + t0 + r) * 512;
    float s = 0.f;
#pragma unroll
    for (int d = 0; d < 8; ++d) s += hp[lane + d * 64] * wl[lane + d * 64];
#pragma unroll
    for (int off = 32; off > 0; off >>= 1) s += __shfl_xor(s, off);
    if (lane == 0) {
      float v = s + bias;
      if (SIG) v = 1.0f / (1.0f + expf(-v));
      out[bb * 512 + t0 + r] = v;
    }
  }
}

// ---------------------------------------------------------------------------
// Rank-based top-k (replaces 48-iteration serial argmax: 90us -> ~4us).
// rank(t) = #{t' : s[t']>s[t] || (s[t']==s[t] && t'<t)}; select rank<K.
// Identical selection + ordering to iterative argmax / jax.lax.top_k.
// ---------------------------------------------------------------------------
__global__ __launch_bounds__(256) void topk_fwd_k(const float* __restrict__ scores,
                                                  int* __restrict__ fwd_idx,
                                                  int* __restrict__ fwd_mask) {
  int b = blockIdx.x, tid = threadIdx.x;
  __shared__ float sv[512];
  __shared__ int flg[512];
  for (int t = tid; t < 512; t += 256)
    sv[t] = (t < NCAND) ? scores[b * 512 + t] : -3.0e38f;
  __syncthreads();
  const float4* sv4 = (const float4*)sv;
#pragma unroll
  for (int h = 0; h < 2; ++h) {
    int t = tid + (h << 8);
    float s = sv[t];
    int cnt = 0;
    for (int t2 = 0; t2 < 128; ++t2) {
      float4 o = sv4[t2];
      int base = t2 << 2;
      cnt += (o.x > s) || (o.x == s && (base + 0) < t);
      cnt += (o.y > s) || (o.y == s && (base + 1) < t);
      cnt += (o.z > s) || (o.z == s && (base + 2) < t);
      cnt += (o.w > s) || (o.w == s && (base + 3) < t);
    }
    int f = (cnt < NFWD) ? 1 : 0;
    flg[t] = f;
    fwd_mask[b * 512 + t] = f;
  }
  __syncthreads();
  // compact ascending by index (fwd_idx is sorted in the reference)
#pragma unroll
  for (int h = 0; h < 2; ++h) {
    int t = tid + (h << 8);
    if (flg[t]) {
      int pos = 0;
      for (int t2 = 0; t2 < t; ++t2) pos += flg[t2];
      fwd_idx[b * NFWD + pos] = t;
    }
  }
}

__global__ __launch_bounds__(256) void topk_retro_k(const float* __restrict__ gs,
                                                    const int* __restrict__ fwd_mask,
                                                    int* __restrict__ sel) {
  int b = blockIdx.x, tid = threadIdx.x;
  __shared__ float sv[512];
  for (int t = tid; t < 512; t += 256) {
    float v;
    if (t < NCAND) v = fwd_mask[b * 512 + t] ? -1.0e9f : gs[b * 512 + t];
    else v = -3.0e38f;
    sv[t] = v;
  }
  __syncthreads();
  const float4* sv4 = (const float4*)sv;
#pragma unroll
  for (int h = 0; h < 2; ++h) {
    int t = tid + (h << 8);
    float s = sv[t];
    int cnt = 0;
    for (int t2 = 0; t2 < 128; ++t2) {
      float4 o = sv4[t2];
      int base = t2 << 2;
      cnt += (o.x > s) || (o.x == s && (base + 0) < t);
      cnt += (o.y > s) || (o.y == s && (base + 1) < t);
      cnt += (o.z > s) || (o.z == s && (base + 2) < t);
      cnt += (o.w > s) || (o.w == s && (base + 3) < t);
    }
    if (cnt < NRETRO) sel[b * NRETRO + cnt] = t;   // slot = rank (desc order)
  }
}

__global__ __launch_bounds__(512) void context_red_k(const float* __restrict__ part,
                                                     float* __restrict__ ctx) {
  int b = blockIdx.x, d = threadIdx.x;
  float s = 0.f;
#pragma unroll
  for (int c = 0; c < 8; ++c) s += part[(size_t)((b << 3) + c) * 512 + d];
  ctx[b * 512 + d] = s * (1.0f / 512.0f);
}

// gather fwd rows -> planes (for q MFMA gemm)
__global__ __launch_bounds__(256) void fwdh_gather_p(const u16* __restrict__ Hh,
                                                     const u16* __restrict__ Hl,
                                                     const int* __restrict__ fwd_idx,
                                                     u16* __restrict__ Fh, u16* __restrict__ Fl) {
  int idx = blockIdx.x * 256 + threadIdx.x;   // 3072*512
  int d = idx & 511, r = idx >> 9;
  int b = r / NFWD, i = r % NFWD;
  int t = fwd_idx[b * NFWD + i];
  int srow = b * 512 + t;
  int si = srow * 512 + (d & ~63) + ((d & 63) ^ ((srow & 7) << 3));
  float v = bf2f(Hh[si]) + bf2f(Hl[si]);
  u16 h = bft(v);
  int di = r * 512 + (d & ~63) + ((d & 63) ^ ((r & 7) << 3));
  Fh[di] = h; Fl[di] = f2bf(v - bf2f(h));
}

// gather retro rows -> memory[48:64] fp32
__global__ __launch_bounds__(256) void retro_gather_p(const u16* __restrict__ Hh,
                                                      const u16* __restrict__ Hl,
                                                      const int* __restrict__ sel,
                                                      float* __restrict__ mem) {
  int idx = blockIdx.x * 256 + threadIdx.x;
  int d = idx & 511, r = idx >> 9, b = r >> 4, j = r & 15;
  int t = sel[b * NRETRO + j];
  int srow = b * 512 + t;
  int si = srow * 512 + (d & ~63) + ((d & 63) ^ ((srow & 7) << 3));
  mem[((size_t)b * 64 + NFWD + j) * 512 + d] = bf2f(Hh[si]) + bf2f(Hl[si]);
}

// S[b,k,t] = q.k / sqrt(512); kk = kvu cols 0-511, stride 1024
__global__ __launch_bounds__(256) void s_k(const float* __restrict__ q,
                                           const u16* __restrict__ kk,
                                           float* __restrict__ S) {
  int b = blockIdx.y, t0 = blockIdx.x * 64;
  int tid = threadIdx.x, tq = tid & 15, kq = tid >> 4;
  __shared__ float qs[16][49];
  __shared__ float ks[16][68];
  float acc[3][4] = {};
  for (int dc = 0; dc < 512; dc += 16) {
    for (int e = tid; e < 768; e += 256) {
      int d = e / 48, k2 = e % 48;
      qs[d][k2] = q[((size_t)b * 48 + k2) * 512 + dc + d];
    }
    for (int e = tid; e < 1024; e += 256) {
      int t = e >> 4, d = e & 15;
      ks[d][t] = bf2f(kk[((size_t)b * 512 + t0 + t) * 1024 + dc + d]);
    }
    __syncthreads();
#pragma unroll
    for (int d = 0; d < 16; ++d) {
      float4 kv = *(const float4*)&ks[d][tq << 2];
#pragma unroll
      for (int j = 0; j < 3; ++j) {
        float qv = qs[d][kq * 3 + j];
        acc[j][0] += qv * kv.x; acc[j][1] += qv * kv.y;
        acc[j][2] += qv * kv.z; acc[j][3] += qv * kv.w;
      }
    }
    __syncthreads();
  }
  const float sc = 0.044194173824159216f;
#pragma unroll
  for (int j = 0; j < 3; ++j) {
    int k = kq * 3 + j;
    float4 o; o.x = acc[j][0] * sc; o.y = acc[j][1] * sc;
    o.z = acc[j][2] * sc; o.w = acc[j][3] * sc;
    *(float4*)&S[((size_t)b * 48 + k) * 512 + t0 + (tq << 2)] = o;
  }
}

__global__ __launch_bounds__(256) void softmax_k(float* __restrict__ S) {
  float* p = S + (size_t)blockIdx.x * 512;
  int tid = threadIdx.x;
  __shared__ float red[256];
  __shared__ float stat[2];
  float v0 = p[tid], v1 = p[tid + 256];
  red[tid] = fmaxf(v0, v1);
  __syncthreads();
  for (int s = 128; s > 0; s >>= 1) { if (tid < s) red[tid] = fmaxf(red[tid], red[tid + s]); __syncthreads(); }
  if (tid == 0) stat[0] = red[0];
  __syncthreads();
  float mx = stat[0];
  float e0 = expf(v0 - mx), e1 = expf(v1 - mx);
  red[tid] = e0 + e1;
  __syncthreads();
  for (int s = 128; s > 0; s >>= 1) { if (tid < s) red[tid] += red[tid + s]; __syncthreads(); }
  if (tid == 0) stat[1] = 1.0f / red[0];
  __syncthreads();
  float inv = stat[1];
  p[tid] = e0 * inv; p[tid + 256] = e1 * inv;
}

// attn_out = P @ V; V = kvu cols 512-1023 (vvp=base+512), stride 1024;
// outputs swizzled hi/lo planes for the wo MFMA gemm
__global__ __launch_bounds__(256) void pv_k(const float* __restrict__ P,
                                            const u16* __restrict__ vvp,
                                            u16* __restrict__ Ph, u16* __restrict__ Pl) {
  int b = blockIdx.y, d0 = blockIdx.x * 64;
  int tid = threadIdx.x, dq = tid & 15, kq = tid >> 4;
  __shared__ float ps[16][49];
  __shared__ float vs[16][68];
  float acc[3][4] = {};
  for (int tc = 0; tc < 512; tc += 16) {
    for (int e = tid; e < 768; e += 256) {
      int t = e / 48, k2 = e % 48;
      ps[t][k2] = P[((size_t)b * 48 + k2) * 512 + tc + t];
    }
    for (int e = tid; e < 1024; e += 256) {
      int t = e >> 6, d = e & 63;
      vs[t][d] = bf2f(vvp[((size_t)b * 512 + tc + t) * 1024 + d0 + d]);
    }
    __syncthreads();
#pragma unroll
    for (int t = 0; t < 16; ++t) {
      float4 vval = *(const float4*)&vs[t][dq << 2];
#pragma unroll
      for (int j = 0; j < 3; ++j) {
        float pp = ps[t][kq * 3 + j];
        acc[j][0] += pp * vval.x; acc[j][1] += pp * vval.y;
        acc[j][2] += pp * vval.z; acc[j][3] += pp * vval.w;
      }
    }
    __syncthreads();
  }
#pragma unroll
  for (int j = 0; j < 3; ++j) {
    int k = kq * 3 + j;
    int row = b * 48 + k;
    int c = (row & 7) << 3;
    int di = row * 512 + d0 + ((dq << 2) ^ c);
    float v0 = acc[j][0], v1 = acc[j][1], v2 = acc[j][2], v3 = acc[j][3];
    u16 h0 = bft(v0), h1 = bft(v1), h2 = bft(v2), h3 = bft(v3);
    uint2 hv, lv;
    hv.x = (u32)h0 | ((u32)h1 << 16); hv.y = (u32)h2 | ((u32)h3 << 16);
    lv.x = (u32)f2bf(v0 - bf2f(h0)) | ((u32)f2bf(v1 - bf2f(h1)) << 16);
    lv.y = (u32)f2bf(v2 - bf2f(h2)) | ((u32)f2bf(v3 - bf2f(h3)) << 16);
    *(uint2*)&Ph[di] = hv;
    *(uint2*)&Pl[di] = lv;
  }
}

__global__ __launch_bounds__(512) void qh_p_k(const u16* __restrict__ Hh,
                                              const u16* __restrict__ Hl,
                                              const float* __restrict__ rq_w,
                                              const float* __restrict__ rq_b,
                                              float* __restrict__ qh) {
  int b = blockIdx.x, d = threadIdx.x;
  __shared__ float hr[512];
  int row = b * 512 + 510;                       // (510&7)=6 -> key 48
  int idx = row * 512 + (d & ~63) + ((d & 63) ^ 48);
  hr[d] = bf2f(Hh[idx]) + bf2f(Hl[idx]);
  __syncthreads();
  float s = 0.f;
  for (int k = 0; k < 512; ++k) s += hr[k] * rq_w[(size_t)k * 512 + d];
  qh[b * 512 + d] = s + rq_b[d];
}

// mem softmax + ctx; emits ctx as swizzled hi/lo planes for out_mgemm
__global__ __launch_bounds__(512) void mem_attn_k(const float* __restrict__ mem,
                                                  const float* __restrict__ qh,
                                                  u16* __restrict__ ctxh,
                                                  u16* __restrict__ ctxl) {
  int b = blockIdx.x, tid = threadIdx.x;
  __shared__ float qv[512];
  __shared__ float sc[64];
  qv[tid] = qh[b * 512 + tid];
  __syncthreads();
  if (tid < 64) {
    const float* mp = mem + ((size_t)b * 64 + tid) * 512;
    float s = 0.f;
    for (int d = 0; d < 512; ++d) s += mp[d] * qv[d];
    float mx = s;
#pragma unroll
    for (int off = 32; off > 0; off >>= 1) mx = fmaxf(mx, __shfl_xor(mx, off));
    float e = expf(s - mx);
    float sum = e;
#pragma unroll
    for (int off = 32; off > 0; off >>= 1) sum += __shfl_xor(sum, off);
    sc[tid] = e / sum;
  }
  __syncthreads();
  float a = 0.f;
  for (int m = 0; m < 64; ++m) a += sc[m] * mem[((size_t)b * 64 + m) * 512 + tid];
  int di = b * 512 + (tid & ~63) + ((tid & 63) ^ ((b & 7) << 3));
  u16 h = bft(a);
  ctxh[di] = h; ctxl[di] = f2bf(a - bf2f(h));
}

extern "C" void kernel_launch(void* const* d_in, const int* in_sizes, int n_in,
                              void* d_out, int out_size, void* d_ws, size_t ws_size,
                              hipStream_t stream) {
  const int*  seq    = (const int*)d_in[0];
  const void* embed  = d_in[1];
  const void* ff_w1  = d_in[2];
  const void* ff_b1  = d_in[3];
  const void* ff_w2  = d_in[4];
  const void* ff_b2  = d_in[5];
  const void* ln_g   = d_in[6];
  const void* ln_b   = d_in[7];
  const void* fg_w   = d_in[8];
  const void* fg_b   = d_in[9];
  const void* nw_w1  = d_in[10];
  const void* nw_b1  = d_in[11];
  const void* nw_w2  = d_in[12];
  const void* nw_b2  = d_in[13];
  const void* wq     = d_in[14];
  const void* bq     = d_in[15];
  const void* wk     = d_in[16];
  const void* bk     = d_in[17];
  const void* wv     = d_in[18];
  const void* bv     = d_in[19];
  const void* wo     = d_in[20];
  const void* bo     = d_in[21];
  const void* rq_w   = d_in[22];
  const void* rq_b   = d_in[23];
  const void* out_w  = d_in[24];
  const void* out_b  = d_in[25];
  float* out = (float*)d_out;

  // ---- workspace (float units), NEED = 43,778,048 f
  float* ws = (float*)d_ws;
  // region A [0, 16,777,216 f): hidden fp32 -> g1f fp32 -> kvu u16[32768][1024]
  float* hidden = ws;
  float* g1f    = ws;
  u16*   kvu    = (u16*)ws;                     // 64 MB
  // region R [16,777,216, 33,554,432 f):
  //   FFN phase (per 8192-row chunk): h0 planes (16MB) + actH planes (32MB)
  //   then: H planes (64MB); finally: WoT bf16 [50304][512] (51.5MB)
  u16* h0h   = (u16*)(ws + 16777216);           // 8192x512 u16
  u16* h0l   = h0h + 4194304;
  u16* actHh = (u16*)(ws + 20971520);           // 8192x1024 u16
  u16* actHl = actHh + 8388608;
  u16* Hh    = (u16*)(ws + 16777216);           // 32768x512 planes (post-LN)
  u16* Hl    = Hh + 16777216;
  u16* WoT   = (u16*)(ws + 16777216);           // 50304x512 bf16 (over dead H)
  // region S1
  size_t S0 = 33554432;
  float* fwd_scores = ws + S0;
  float* gs         = ws + S0 + 32768;
  float* context    = ws + S0 + 65536;
  float* gate_bias  = ws + S0 + 98304;
  float* qh         = ws + S0 + 131072;
  u16*   ctxh       = (u16*)(ws + S0 + 163840); // ctx hi/lo planes (128KB slot)
  u16*   ctxl       = ctxh + 32768;
  int*   fwd_idx    = (int*)(ws + S0 + 196608);
  int*   sel        = (int*)(ws + S0 + 199680);
  int*   fwd_mask   = (int*)(ws + S0 + 200704);
  int*   flagp      = (int*)(ws + S0 + 233472);
  float* bkv        = ws + S0 + 236544;         // 1024 f concat bias
  float* cpart      = ws + S0 + 262144;         // context partials (dies early)
  u16*   Fh         = (u16*)(ws + S0 + 262144); // fwd_h planes (after cpart dead)
  u16*   Fl         = Fh + 1572864;
  float* q          = ws + S0 + 1835008;
  float* Smat       = ws + S0 + 3407872;
  // weight planes pack (dead before s_k overwrites as Smat / pv writes Ph)
  u16* W0    = (u16*)(ws + S0 + 3407872);
  u16* WTnh  = W0;            u16* WTnl  = W0 + 262144;
  u16* WTkvh = W0 + 524288;   u16* WTkvl = W0 + 1048576;  // 1024x512 each
  u16* WT1h  = W0 + 1572864;  u16* WT1l  = W0 + 2097152;  // 1024x512 each
  u16* WT2h  = W0 + 2621440;  u16* WT2l  = W0 + 3145728;  // 512x1024 each
  u16* Ph    = (u16*)(ws + S0 + 4980736);       // attn planes (pv out)
  u16* Pl    = Ph + 1572864;
  u16* Wq0   = (u16*)(ws + S0 + 6553600);
  u16* WTqh  = Wq0;          u16* WTql = Wq0 + 262144;
  u16* WToh  = Wq0 + 524288; u16* WTol = Wq0 + 786432;
  float* memory = ws + S0 + 8126464;
  const size_t NEED = (size_t)(33554432 + 10223616) * 4;

  if (ws_size < NEED) {
    float val = 500.0f + (float)(ws_size >> 20);
    sentinel_k<<<(out_size + 255) / 256, 256, 0, stream>>>(out, out_size, val);
    return;
  }

  detect_k<<<1, 1, 0, stream>>>((const u32*)embed, flagp);

  // one-time weight transpose+split (swizzled bf16 planes)
  tsplit_k<<<512, 256, 0, stream>>>((const float*)ff_w1, WT1h, WT1l, 512, 1024);
  tsplit_k<<<512, 256, 0, stream>>>((const float*)ff_w2, WT2h, WT2l, 1024, 512);
  tsplit_k<<<256, 256, 0, stream>>>((const float*)nw_w1, WTnh, WTnl, 512, 512);
  tsplit_k<<<256, 256, 0, stream>>>((const float*)wk, WTkvh, WTkvl, 512, 512);
  tsplit_k<<<256, 256, 0, stream>>>((const float*)wv, WTkvh + 512*512, WTkvl + 512*512, 512, 512);
  tsplit_k<<<256, 256, 0, stream>>>((const float*)wq, WTqh, WTql, 512, 512);
  tsplit_k<<<256, 256, 0, stream>>>((const float*)wo, WToh, WTol, 512, 512);
  concat2_k<<<4, 256, 0, stream>>>((const float*)bk, (const float*)bv, bkv);

  // FFN: 4 M-chunks of 8192; merged N=1024 FFN1 + K=1024 FFN2 per chunk
  for (int mc = 0; mc < 4; ++mc) {
    const int* seqp = seq + mc * 8192;
    float* hid = hidden + (size_t)mc * 8192 * 512;
    gsplit_k<<<2048, 256, 0, stream>>>((const float*)embed, seqp, h0h, h0l);
    mgemm_k<8,8,0,1,2><<<512, 256, 0, stream>>>(
        h0h, h0l, WT1h, WT1l, 512, 512, 0,
        (const float*)ff_b1, 0, nullptr, nullptr, nullptr,
        nullptr, nullptr, actHh, actHl, 1024);
    mgemm_k<4,16,1,0,0><<<256, 256, 0, stream>>>(
        actHh, actHl, WT2h, WT2l, 1024, 1024, 0,
        (const float*)ff_b2, 0, h0h, h0l, nullptr,
        hid, nullptr, nullptr, nullptr, 512);
  }
  // LayerNorm -> H planes
  ln_split_k<<<32768, 256, 0, stream>>>(hidden, (const float*)ln_g, (const float*)ln_b, Hh, Hl);
  // FUSED fwd gate scores + context partials
  gatectx_k<<<dim3(8,64), 256, 0, stream>>>(Hh, Hl, (const float*)fg_w, (const float*)fg_b,
                                            fwd_scores, cpart);
  topk_fwd_k<<<64, 256, 0, stream>>>(fwd_scores, fwd_idx, fwd_mask);
  context_red_k<<<64, 512, 0, stream>>>(cpart, context);
  // gate_bias = context @ nw_w1[512:,:] + nw_b1 (tiny, SIMT)
  gemm_k<0,0,0,0,0><<<dim3(8,1), 256, 0, stream>>>(
      context, 512, nullptr, nullptr, nw_w1, 512, (size_t)512*512, nw_b1, 0,
      nullptr, nullptr, 0, nullptr, 0, 0, gate_bias, 512, 512, flagp);
  // g1 = relu(H @ nw_w1[:512] + gate_bias)
  mgemm_k<4,8,2,1,0><<<1024, 256, 0, stream>>>(
      Hh, Hl, WTnh, WTnl, 512, 512, 0,
      nullptr, 0, nullptr, nullptr, gate_bias,
      g1f, nullptr, nullptr, nullptr, 512);
  score_k<1><<<dim3(8,64), 256, 0, stream>>>(g1f, nw_w2, nw_b2, gs, flagp);
  topk_retro_k<<<64, 256, 0, stream>>>(gs, fwd_mask, sel);
  retro_gather_p<<<2048, 256, 0, stream>>>(Hh, Hl, sel, memory);
  // q projection (MFMA, M=3072)
  fwdh_gather_p<<<6144, 256, 0, stream>>>(Hh, Hl, fwd_idx, Fh, Fl);
  mgemm_k<4,8,0,0,0><<<96, 256, 0, stream>>>(
      Fh, Fl, WTqh, WTql, 512, 512, 0,
      (const float*)bq, 0, nullptr, nullptr, nullptr,
      q, nullptr, nullptr, nullptr, 512);
  // K,V fused projection -> kvu[m][1024] bf16 (K cols 0-511, V cols 512-1023)
  mgemm_k<8,8,0,0,1><<<2048, 256, 0, stream>>>(
      Hh, Hl, WTkvh, WTkvl, 512, 512, 0,
      bkv, 0, nullptr, nullptr, nullptr,
      nullptr, kvu, nullptr, nullptr, 1024);
  // attention
  s_k<<<dim3(8,64), 256, 0, stream>>>(q, kvu, Smat);
  softmax_k<<<3072, 256, 0, stream>>>(Smat);
  pv_k<<<dim3(8,64), 256, 0, stream>>>(Smat, kvu + 512, Ph, Pl);
  // re_slots = attn @ wo + bo -> memory[0:48] (OUT=3 row remap)
  mgemm_k<4,8,0,0,3><<<96, 256, 0, stream>>>(
      Ph, Pl, WToh, WTol, 512, 512, 0,
      (const float*)bo, 0, nullptr, nullptr, nullptr,
      memory, nullptr, nullptr, nullptr, 512);
  // qh, memory softmax (-> ctx planes), vocab MFMA projection
  qh_p_k<<<64, 512, 0, stream>>>(Hh, Hl, (const float*)rq_w, (const float*)rq_b, qh);
  mem_attn_k<<<64, 512, 0, stream>>>(memory, qh, ctxh, ctxl);
  tout_k<<<16 * 1572, 256, 0, stream>>>((const float*)out_w, WoT);
  out_mgemm_k<<<393, 256, 0, stream>>>(ctxh, ctxl, WoT, (const float*)out_b, out);
}

// Round 6
// 1160.115 us; speedup vs baseline: 1.0808x; 1.0281x over previous
//
#include <hip/hip_runtime.h>

typedef unsigned short u16;
typedef unsigned int u32;

#define VV 50257
#define NCAND 509
#define NFWD 48
#define NRETRO 16

typedef __attribute__((ext_vector_type(8))) short bf16x8;
typedef __attribute__((ext_vector_type(4))) float f32x4;

__device__ __forceinline__ float bf2f(u16 u) {
  union { u32 i; float f; } v; v.i = ((u32)u) << 16; return v.f;
}
__device__ __forceinline__ u16 f2bf(float f) {
  union { float f; u32 u; } v; v.f = f;
  u32 u = v.u; u += 0x7fffu + ((u >> 16) & 1u); return (u16)(u >> 16);
}
// truncating bf16 (hi part of a hi/lo split; lo = v - bf2f(hi) then RNE)
__device__ __forceinline__ u16 bft(float f) {
  union { float f; u32 u; } v; v.f = f; return (u16)(v.u >> 16);
}
__device__ __forceinline__ float ldsel(const void* p, size_t i, int isbf) {
  return isbf ? bf2f(((const u16*)p)[i]) : ((const float*)p)[i];
}

// async global->LDS, 16B per lane; LDS dest = base + lane*16 (wave-uniform base)
__device__ __forceinline__ void g2l16(const u16* g, u16* l) {
  __builtin_amdgcn_global_load_lds((const __attribute__((address_space(1))) u32*)g,
                                   (__attribute__((address_space(3))) u32*)l, 16, 0, 0);
}

// dtype detector (for the SIMT gate_bias kernel; runtime shows fp32)
__global__ void detect_k(const u32* __restrict__ w, int* __restrict__ flag) {
  int bf = 1;
  for (int i = 0; i < 16; ++i) {
    u32 b1 = (w[i] >> 8) & 0x7fu;
    if (!(b1 >= 0x30u && b1 < 0x40u)) bf = 0;
  }
  *flag = bf;
}

__global__ void sentinel_k(float* __restrict__ out, int n, float val) {
  int i = blockIdx.x * 256 + threadIdx.x;
  if (i < n) out[i] = val;
}

// ---------------------------------------------------------------------------
// Weight transform: W[K][N] fp32 -> hi/lo bf16 planes T[N][K], XOR-swizzled
// within each 64-elem k-block: k' = (k&~63) | ((k&63) ^ ((n&7)<<3)).
// ---------------------------------------------------------------------------
__global__ __launch_bounds__(256) void tsplit_k(const float* __restrict__ W,
                                                u16* __restrict__ Th, u16* __restrict__ Tl,
                                                int K, int N) {
  __shared__ float tt[32][33];
  int nt = N >> 5;
  int n0 = (blockIdx.x % nt) << 5;
  int k0 = (blockIdx.x / nt) << 5;
  int c = threadIdx.x & 31, r = threadIdx.x >> 5;   // r in 0..7
#pragma unroll
  for (int i = 0; i < 32; i += 8) tt[r + i][c] = W[(size_t)(k0 + r + i) * N + n0 + c];
  __syncthreads();
#pragma unroll
  for (int i = 0; i < 32; i += 8) {
    int n = n0 + r + i, k = k0 + c;
    float v = tt[c][r + i];
    u16 h = bft(v);
    int idx = n * K + (k & ~63) + ((k & 63) ^ ((n & 7) << 3));
    Th[idx] = h; Tl[idx] = f2bf(v - bf2f(h));
  }
}

// out_w[512][VV] fp32 -> single-bf16 swizzled WoT[50304][512] (pad rows zeroed)
__global__ __launch_bounds__(256) void tout_k(const float* __restrict__ W,
                                              u16* __restrict__ WoT) {
  __shared__ float tt[32][33];
  const int nt = 1572;
  int n0 = (blockIdx.x % nt) << 5;
  int k0 = (blockIdx.x / nt) << 5;
  int c = threadIdx.x & 31, r = threadIdx.x >> 5;
#pragma unroll
  for (int i = 0; i < 32; i += 8) {
    int n = n0 + c;
    tt[r + i][c] = (n < VV) ? W[(size_t)(k0 + r + i) * VV + n] : 0.f;
  }
  __syncthreads();
#pragma unroll
  for (int i = 0; i < 32; i += 8) {
    int n = n0 + r + i, k = k0 + c;
    WoT[(size_t)n * 512 + (k & ~63) + ((k & 63) ^ ((n & 7) << 3))] = f2bf(tt[c][r + i]);
  }
}

// concat bias [bk | bv] -> bkv[1024]
__global__ void concat2_k(const float* __restrict__ a, const float* __restrict__ b,
                          float* __restrict__ o) {
  int i = blockIdx.x * 256 + threadIdx.x;
  if (i < 1024) o[i] = (i < 512) ? a[i] : b[i - 512];
}

// gathered embed rows -> swizzled hi/lo planes (chunk of 8192 rows)
__global__ __launch_bounds__(256) void gsplit_k(const float* __restrict__ embed,
                                                const int* __restrict__ seqp,
                                                u16* __restrict__ Ph, u16* __restrict__ Pl) {
  int g = blockIdx.x * 256 + threadIdx.x;   // over 8192*64
  int m = g >> 6, j8 = (g & 63) << 3;
  const float* s = embed + (size_t)seqp[m] * 512 + j8;
  float4 a = *(const float4*)s;
  float4 b = *(const float4*)(s + 4);
  u16 h0 = bft(a.x), h1 = bft(a.y), h2 = bft(a.z), h3 = bft(a.w);
  u16 h4 = bft(b.x), h5 = bft(b.y), h6 = bft(b.z), h7 = bft(b.w);
  uint4 hv, lv;
  hv.x = (u32)h0 | ((u32)h1 << 16); hv.y = (u32)h2 | ((u32)h3 << 16);
  hv.z = (u32)h4 | ((u32)h5 << 16); hv.w = (u32)h6 | ((u32)h7 << 16);
  lv.x = (u32)f2bf(a.x - bf2f(h0)) | ((u32)f2bf(a.y - bf2f(h1)) << 16);
  lv.y = (u32)f2bf(a.z - bf2f(h2)) | ((u32)f2bf(a.w - bf2f(h3)) << 16);
  lv.z = (u32)f2bf(b.x - bf2f(h4)) | ((u32)f2bf(b.y - bf2f(h5)) << 16);
  lv.w = (u32)f2bf(b.z - bf2f(h6)) | ((u32)f2bf(b.w - bf2f(h7)) << 16);
  int di = m * 512 + (j8 ^ ((m & 7) << 3));
  *(uint4*)&Ph[di] = hv;
  *(uint4*)&Pl[di] = lv;
}

// ---------------------------------------------------------------------------
// 3-pass split-bf16 MFMA GEMM: C[M, NT*64] = epi(A @ B).  K = KST*64.
// C ~= Ah.Bh + Al.Bh + Ah.Bl  (AlBl ~2^-16 dropped).
// Tile 128m x 64n, 4 waves 2x2 (wave = 64m x 32n); LDS 48KB -> 3 blocks/CU
// (old 128x128/64KB ran 2 blocks/CU: Occupancy 20%, MfmaUtil 50%).
// ADDM: 1 = + residual planes (stride 512, n<512); 2 = + addf[(m>>9)*512+n]
// OUT : 0 fp32 Cf; 1 bf16 Cb; 2 swizzled hi/lo planes (ldc);
//       3 fp32 row remap m -> (m/48)*64 + m%48 (memory[0:48] slots);
//       4 fused row-dot: gpart[m*NT+nx] = sum_n relu(v)*w2g[n] (g1->gs path,
//         kills the 64MB g1 write + 64MB score read)
// ---------------------------------------------------------------------------
template<int NT, int KST, int ADDM, int RELU, int OUT>
__global__ __launch_bounds__(256) void mgemm_k(
    const u16* __restrict__ Ah, const u16* __restrict__ Al,
    const u16* __restrict__ Bh, const u16* __restrict__ Bl,
    int lda, int ldb, int koff,
    const float* __restrict__ biasf, int boff,
    const u16* __restrict__ Rh, const u16* __restrict__ Rl,
    const float* __restrict__ addf,
    const float* __restrict__ w2g, float* __restrict__ gpart,
    float* __restrict__ Cf, u16* __restrict__ Cb,
    u16* __restrict__ Ohi, u16* __restrict__ Olo, int ldc)
{
  __shared__ __align__(16) u16 lds[24576];   // Ah/Al 128x64 + Bh/Bl 64x64 (48KB)
  int tid = threadIdx.x;
  int cpx = gridDim.x >> 3;                  // XCD-chunked swizzle (grid % 8 == 0)
  int bid = blockIdx.x;
  int wg = (bid & 7) * cpx + (bid >> 3);
  int my = wg / NT, nx = wg % NT;
  int m0 = my << 7, n0 = nx << 6;
  int lane = tid & 63, wid = tid >> 6;

  // staging: wave w stages plane w (0=Ah,1=Al,2=Bh,3=Bl)
  const u16* gw; int stw; int lb;
  if (wid == 0)      { gw = Ah + (size_t)m0 * lda;        stw = lda; lb = 0; }
  else if (wid == 1) { gw = Al + (size_t)m0 * lda;        stw = lda; lb = 8192; }
  else if (wid == 2) { gw = Bh + (size_t)n0 * ldb + koff; stw = ldb; lb = 16384; }
  else               { gw = Bl + (size_t)n0 * ldb + koff; stw = ldb; lb = 20480; }
  const u16* gl = gw + (size_t)(lane >> 3) * stw + ((lane & 7) << 3);

  f32x4 acc[4][2] = {};
  int wr = wid >> 1, wc = wid & 1;
  int cl = lane & 15;
  int kq8 = (lane >> 4) << 3;
  int swz = (cl & 7) << 3;

  for (int k0 = 0; k0 < KST * 64; k0 += 64) {
    if (wid < 2) {
#pragma unroll
      for (int i = 0; i < 16; ++i)
        g2l16(gl + (size_t)(i << 3) * stw + k0, &lds[lb + (i << 9)]);
    } else {
#pragma unroll
      for (int i = 0; i < 8; ++i)
        g2l16(gl + (size_t)(i << 3) * stw + k0, &lds[lb + (i << 9)]);
    }
    __syncthreads();
#pragma unroll
    for (int kt = 0; kt < 2; ++kt) {
      int kA = ((kt << 5) + kq8) ^ swz;
      bf16x8 bh[2], blo[2];
#pragma unroll
      for (int j = 0; j < 2; ++j) {
        int ib = (((wc << 5) + (j << 4) + cl) << 6) + kA;
        bh[j]  = *(const bf16x8*)&lds[16384 + ib];
        blo[j] = *(const bf16x8*)&lds[20480 + ib];
      }
#pragma unroll
      for (int i2 = 0; i2 < 4; ++i2) {
        int ia = (((wr << 6) + (i2 << 4) + cl) << 6) + kA;
        bf16x8 ah  = *(const bf16x8*)&lds[ia];
        bf16x8 alo = *(const bf16x8*)&lds[8192 + ia];
#pragma unroll
        for (int j = 0; j < 2; ++j) {
          acc[i2][j] = __builtin_amdgcn_mfma_f32_16x16x32_bf16(ah,  bh[j],  acc[i2][j], 0, 0, 0);
          acc[i2][j] = __builtin_amdgcn_mfma_f32_16x16x32_bf16(alo, bh[j],  acc[i2][j], 0, 0, 0);
          acc[i2][j] = __builtin_amdgcn_mfma_f32_16x16x32_bf16(ah,  blo[j], acc[i2][j], 0, 0, 0);
        }
      }
    }
    __syncthreads();
  }

  // C/D layout: col = lane&15, row = (lane>>4)*4 + reg  [m89/m91]
  int rq = (lane >> 4) << 2;
  int mb = m0 + (wr << 6);
  int nb = n0 + (wc << 5);

  if (OUT == 4) {
    // fused per-row dot with w2g over this tile's 64 cols
    float rs[4][4];
#pragma unroll
    for (int i2 = 0; i2 < 4; ++i2)
#pragma unroll
      for (int r = 0; r < 4; ++r) rs[i2][r] = 0.f;
#pragma unroll
    for (int j = 0; j < 2; ++j) {
      int n = nb + (j << 4) + cl;
      float w2 = w2g[n];
      float bi = biasf ? biasf[boff + n] : 0.f;
#pragma unroll
      for (int i2 = 0; i2 < 4; ++i2) {
#pragma unroll
        for (int r = 0; r < 4; ++r) {
          int m = mb + (i2 << 4) + rq + r;
          float v = acc[i2][j][r] + bi;
          if (ADDM == 2) v += addf[((m >> 9) << 9) + n];
          if (RELU) v = fmaxf(v, 0.f);
          rs[i2][r] += v * w2;
        }
      }
    }
#pragma unroll
    for (int i2 = 0; i2 < 4; ++i2)
#pragma unroll
      for (int r = 0; r < 4; ++r) {
        float s = rs[i2][r];
#pragma unroll
        for (int off = 8; off > 0; off >>= 1) s += __shfl_xor(s, off);
        rs[i2][r] = s;
      }
    float* lf = (float*)lds;     // safe: all LDS reads drained at last barrier
    if (cl == 0) {
#pragma unroll
      for (int i2 = 0; i2 < 4; ++i2)
#pragma unroll
        for (int r = 0; r < 4; ++r)
          lf[(wr << 7) + (wc << 6) + (i2 << 4) + rq + r] = rs[i2][r];
    }
    __syncthreads();
    if (tid < 128) {
      int w = tid >> 6, m64 = tid & 63;
      float s = lf[(w << 7) + m64] + lf[(w << 7) + 64 + m64];
      gpart[(size_t)(m0 + (w << 6) + m64) * NT + nx] = s;
    }
    return;
  }

#pragma unroll
  for (int j = 0; j < 2; ++j) {
    int n = nb + (j << 4) + cl;
    float bi = biasf ? biasf[boff + n] : 0.f;
#pragma unroll
    for (int i2 = 0; i2 < 4; ++i2) {
#pragma unroll
      for (int r = 0; r < 4; ++r) {
        int m = mb + (i2 << 4) + rq + r;
        float v = acc[i2][j][r] + bi;
        if (ADDM == 1) {
          int ridx = m * 512 + (n ^ ((m & 7) << 3));
          v += bf2f(Rh[ridx]) + bf2f(Rl[ridx]);
        }
        if (ADDM == 2) v += addf[((m >> 9) << 9) + n];
        if (RELU) v = fmaxf(v, 0.f);
        if (OUT == 0) Cf[(size_t)m * ldc + n] = v;
        else if (OUT == 1) Cb[(size_t)m * ldc + n] = f2bf(v);
        else if (OUT == 2) {
          u16 h = bft(v);
          size_t oidx = (size_t)m * ldc + (n & ~63) + ((n & 63) ^ ((m & 7) << 3));
          Ohi[oidx] = h; Olo[oidx] = f2bf(v - bf2f(h));
        } else {                       // OUT==3: memory[0:48] slots
          int r64 = (m * 43691) >> 21; // m/48 for m<3072
          int mm = (r64 << 6) + (m - r64 * 48);
          Cf[(size_t)mm * 512 + n] = v;
        }
      }
    }
  }
}

// gs = sigmoid(sum of 8 gpart tiles + nw_b2)
__global__ __launch_bounds__(256) void gs_red_k(const float* __restrict__ gpart,
                                                const float* __restrict__ b2,
                                                float* __restrict__ gs) {
  int m = blockIdx.x * 256 + threadIdx.x;   // 32768
  const float* p = gpart + (size_t)m * 8;
  float t = 0.f;
#pragma unroll
  for (int i = 0; i < 8; ++i) t += p[i];
  float s = t + b2[0];
  gs[m] = 1.0f / (1.0f + expf(-s));
}

// ---------------------------------------------------------------------------
// Vocab MFMA GEMM: out[64][VV] = ctx(hi/lo planes) @ WoT(single bf16) + out_b.
// Tile 64m x 128n, 4 waves (each 64x32), 2 passes (Ah.B + Al.B).
// ---------------------------------------------------------------------------
__global__ __launch_bounds__(256) void out_mgemm_k(
    const u16* __restrict__ ctxh, const u16* __restrict__ ctxl,
    const u16* __restrict__ WoT, const float* __restrict__ ob,
    float* __restrict__ out) {
  __shared__ __align__(16) u16 lds[16384];   // Ah 4096 | Al 4096 | B 8192 (u16)
  int tid = threadIdx.x;
  int n0 = blockIdx.x << 7;
  int lane = tid & 63, wid = tid >> 6;
  const u16* gw; int lb0;
  if (wid == 0)      { gw = ctxh;                         lb0 = 0; }
  else if (wid == 1) { gw = ctxl;                         lb0 = 4096; }
  else if (wid == 2) { gw = WoT + (size_t)n0 * 512;        lb0 = 8192; }
  else               { gw = WoT + (size_t)(n0 + 64) * 512; lb0 = 12288; }
  const u16* gl = gw + (size_t)(lane >> 3) * 512 + ((lane & 7) << 3);

  f32x4 acc[4][2] = {};
  int cl = lane & 15;
  int kq8 = (lane >> 4) << 3;
  int swz = (cl & 7) << 3;

  for (int k0 = 0; k0 < 512; k0 += 64) {
#pragma unroll
    for (int i = 0; i < 8; ++i)
      g2l16(gl + (size_t)(i << 3) * 512 + k0, &lds[lb0 + (i << 9)]);
    __syncthreads();
#pragma unroll
    for (int kt = 0; kt < 2; ++kt) {
      int kA = ((kt << 5) + kq8) ^ swz;
      bf16x8 bw[2];
#pragma unroll
      for (int j = 0; j < 2; ++j) {
        int rB = (wid << 5) + (j << 4) + cl;
        bw[j] = *(const bf16x8*)&lds[8192 + (rB << 6) + kA];
      }
#pragma unroll
      for (int i2 = 0; i2 < 4; ++i2) {
        int ra = ((i2 << 4) + cl) << 6;
        bf16x8 ah  = *(const bf16x8*)&lds[ra + kA];
        bf16x8 alo = *(const bf16x8*)&lds[4096 + ra + kA];
#pragma unroll
        for (int j = 0; j < 2; ++j) {
          acc[i2][j] = __builtin_amdgcn_mfma_f32_16x16x32_bf16(ah,  bw[j], acc[i2][j], 0, 0, 0);
          acc[i2][j] = __builtin_amdgcn_mfma_f32_16x16x32_bf16(alo, bw[j], acc[i2][j], 0, 0, 0);
        }
      }
    }
    __syncthreads();
  }

  int rq = (lane >> 4) << 2;
#pragma unroll
  for (int j = 0; j < 2; ++j) {
    int n = n0 + (wid << 5) + (j << 4) + cl;
    if (n < VV) {
      float bi = ob[n];
#pragma unroll
      for (int i2 = 0; i2 < 4; ++i2)
#pragma unroll
        for (int r = 0; r < 4; ++r)
          out[(size_t)((i2 << 4) + rq + r) * VV + n] = acc[i2][j][r] + bi;
    }
  }
}

// ---------------------------------------------------------------------------
// SIMT GEMM (kept only for the tiny gate_bias matmul, M=64)
// ---------------------------------------------------------------------------
template<int AG, int ADDM, int RELU, int ACC, int OUTBF>
__global__ __launch_bounds__(256) void gemm_k(
    const float* __restrict__ A, int lda,
    const void* __restrict__ gbase, const int* __restrict__ gidx,
    const void* __restrict__ Bw, int ldb, size_t boff,
    const void* __restrict__ bias, size_t bias_eoff,
    const void* __restrict__ adg_base, const int* __restrict__ adg_idx, int adg_ld,
    const float* __restrict__ addf, int add_shift, int addf_ld,
    void* __restrict__ Cv, int ldc, int K,
    const int* __restrict__ flagp)
{
  __shared__ float As[16][68];
  __shared__ float Bs[16][68];
  int isbf = *flagp;
  int tid = threadIdx.x;
  int m0 = blockIdx.y * 64;
  int n0 = blockIdx.x * 64;
  int tx = tid & 15, ty = tid >> 4;
  int arow = tid >> 2;
  int akq  = (tid & 3) << 2;
  int bcol = tid & 63;
  int bk0  = tid >> 6;

  size_t a_off = (size_t)(m0 + arow) * (size_t)lda;
  float acc[4][4] = {};

  for (int k0 = 0; k0 < K; k0 += 16) {
    {
      float4 v = *(const float4*)(A + a_off + k0 + akq);
      As[akq + 0][arow] = v.x;
      As[akq + 1][arow] = v.y;
      As[akq + 2][arow] = v.z;
      As[akq + 3][arow] = v.w;
    }
    if (isbf) {
      const u16* bp = (const u16*)Bw + boff;
#pragma unroll
      for (int l = 0; l < 4; ++l) {
        int kb = bk0 + (l << 2);
        Bs[kb][bcol] = bf2f(bp[(size_t)(k0 + kb) * ldb + n0 + bcol]);
      }
    } else {
      const float* bp = (const float*)Bw + boff;
#pragma unroll
      for (int l = 0; l < 4; ++l) {
        int kb = bk0 + (l << 2);
        Bs[kb][bcol] = bp[(size_t)(k0 + kb) * ldb + n0 + bcol];
      }
    }
    __syncthreads();
#pragma unroll
    for (int k = 0; k < 16; ++k) {
      float4 a4 = *(const float4*)&As[k][ty << 2];
      float4 b4 = *(const float4*)&Bs[k][tx << 2];
      float a[4] = {a4.x, a4.y, a4.z, a4.w};
      float bv[4] = {b4.x, b4.y, b4.z, b4.w};
#pragma unroll
      for (int i = 0; i < 4; ++i)
#pragma unroll
        for (int j = 0; j < 4; ++j) acc[i][j] += a[i] * bv[j];
    }
    __syncthreads();
  }

  int mrow = m0 + (ty << 2);
  int ncol = n0 + (tx << 2);
  float bi4[4] = {0.f, 0.f, 0.f, 0.f};
  if (bias) {
#pragma unroll
    for (int j = 0; j < 4; ++j) bi4[j] = ldsel(bias, bias_eoff + ncol + j, isbf);
  }
#pragma unroll
  for (int i = 0; i < 4; ++i) {
    int m = mrow + i;
    float v[4];
#pragma unroll
    for (int j = 0; j < 4; ++j) v[j] = acc[i][j] + bi4[j];
    if (RELU) {
#pragma unroll
      for (int j = 0; j < 4; ++j) v[j] = fmaxf(v[j], 0.f);
    }
    float4 o; o.x = v[0]; o.y = v[1]; o.z = v[2]; o.w = v[3];
    *(float4*)((float*)Cv + (size_t)m * ldc + ncol) = o;
  }
}

// LayerNorm: fp32 in -> swizzled hi/lo planes out
__global__ __launch_bounds__(256) void ln_split_k(const float* __restrict__ x,
                                                  const float* __restrict__ g,
                                                  const float* __restrict__ bt,
                                                  u16* __restrict__ Hh, u16* __restrict__ Hl) {
  int row = blockIdx.x;
  const float* p = x + (size_t)row * 512;
  int tid = threadIdx.x;
  __shared__ float red[256];
  __shared__ float stat[2];
  float v0 = p[tid], v1 = p[tid + 256];
  red[tid] = v0 + v1;
  __syncthreads();
  for (int s = 128; s > 0; s >>= 1) { if (tid < s) red[tid] += red[tid + s]; __syncthreads(); }
  if (tid == 0) stat[0] = red[0] * (1.0f / 512.0f);
  __syncthreads();
  float mu = stat[0];
  float d0 = v0 - mu, d1 = v1 - mu;
  red[tid] = d0 * d0 + d1 * d1;
  __syncthreads();
  for (int s = 128; s > 0; s >>= 1) { if (tid < s) red[tid] += red[tid + s]; __syncthreads(); }
  if (tid == 0) stat[1] = 1.0f / sqrtf(red[0] * (1.0f / 512.0f) + 1e-5f);
  __syncthreads();
  float inv = stat[1];
  float y0 = d0 * inv * g[tid] + bt[tid];
  float y1 = d1 * inv * g[tid + 256] + bt[tid + 256];
  int c = (row & 7) << 3;
  int i0 = row * 512 + (tid ^ c);
  int i1 = row * 512 + ((tid + 256) ^ c);
  u16 h0 = bft(y0), h1 = bft(y1);
  Hh[i0] = h0; Hl[i0] = f2bf(y0 - bf2f(h0));
  Hh[i1] = h1; Hl[i1] = f2bf(y1 - bf2f(h1));
}

// FUSED: fwd gate scores + context partial sums (one pass over H planes)
__global__ __launch_bounds__(256) void gatectx_k(const u16* __restrict__ Hh,
                                                 const u16* __restrict__ Hl,
                                                 const float* __restrict__ w,
                                                 const float* __restrict__ b,
                                                 float* __restrict__ out,
                                                 float* __restrict__ part) {
  int bb = blockIdx.y, t0 = blockIdx.x * 64;
  __shared__ float wl[512];
  __shared__ float cred[4][512];
  for (int d = threadIdx.x; d < 512; d += 256) wl[d] = w[d];
  int wave = threadIdx.x >> 6, lane = threadIdx.x & 63;
  float ca[8] = {};
  __syncthreads();
  float bias = b[0];
  for (int r = wave; r < 64; r += 4) {
    int grow = bb * 512 + t0 + r;
    int lx = lane ^ ((grow & 7) << 3);
    const u16* ph = Hh + (size_t)grow * 512;
    const u16* pl = Hl + (size_t)grow * 512;
    float s = 0.f;
#pragma unroll
    for (int d = 0; d < 8; ++d) {
      float hv = bf2f(ph[lx + d * 64]) + bf2f(pl[lx + d * 64]);
      ca[d] += hv;
      s += hv * wl[lane + d * 64];
    }
#pragma unroll
    for (int off = 32; off > 0; off >>= 1) s += __shfl_xor(s, off);
    if (lane == 0) out[bb * 512 + t0 + r] = s + bias;
  }
#pragma unroll
  for (int d = 0; d < 8; ++d) cred[wave][lane + d * 64] = ca[d];
  __syncthreads();
  for (int d = threadIdx.x; d < 512; d += 256)
    part[(size_t)((bb << 3) + blockIdx.x) * 512 + d] =
        cred[0][d] + cred[1][d] + cred[2][d] + cred[3][d];
}

// ---------------------------------------------------------------------------
// Rank-based top-k. rank(t) = #{t' better}; select rank < K.
// ---------------------------------------------------------------------------
__global__ __launch_bounds__(256) void topk_fwd_k(const float* __restrict__ scores,
                                                  int* __restrict__ fwd_idx,
                                                  int* __restrict__ fwd_mask) {
  int b = blockIdx.x, tid = threadIdx.x;
  __shared__ float sv[512];
  __shared__ int flg[512];
  for (int t = tid; t < 512; t += 256)
    sv[t] = (t < NCAND) ? scores[b * 512 + t] : -3.0e38f;
  __syncthreads();
  const float4* sv4 = (const float4*)sv;
#pragma unroll
  for (int h = 0; h < 2; ++h) {
    int t = tid + (h << 8);
    float s = sv[t];
    int cnt = 0;
    for (int t2 = 0; t2 < 128; ++t2) {
      float4 o = sv4[t2];
      int base = t2 << 2;
      cnt += (o.x > s) || (o.x == s && (base + 0) < t);
      cnt += (o.y > s) || (o.y == s && (base + 1) < t);
      cnt += (o.z > s) || (o.z == s && (base + 2) < t);
      cnt += (o.w > s) || (o.w == s && (base + 3) < t);
    }
    int f = (cnt < NFWD) ? 1 : 0;
    flg[t] = f;
    fwd_mask[b * 512 + t] = f;
  }
  __syncthreads();
#pragma unroll
  for (int h = 0; h < 2; ++h) {
    int t = tid + (h << 8);
    if (flg[t]) {
      int pos = 0;
      for (int t2 = 0; t2 < t; ++t2) pos += flg[t2];
      fwd_idx[b * NFWD + pos] = t;
    }
  }
}

__global__ __launch_bounds__(256) void topk_retro_k(const float* __restrict__ gs,
                                                    const int* __restrict__ fwd_mask,
                                                    int* __restrict__ sel) {
  int b = blockIdx.x, tid = threadIdx.x;
  __shared__ float sv[512];
  for (int t = tid; t < 512; t += 256) {
    float v;
    if (t < NCAND) v = fwd_mask[b * 512 + t] ? -1.0e9f : gs[b * 512 + t];
    else v = -3.0e38f;
    sv[t] = v;
  }
  __syncthreads();
  const float4* sv4 = (const float4*)sv;
#pragma unroll
  for (int h = 0; h < 2; ++h) {
    int t = tid + (h << 8);
    float s = sv[t];
    int cnt = 0;
    for (int t2 = 0; t2 < 128; ++t2) {
      float4 o = sv4[t2];
      int base = t2 << 2;
      cnt += (o.x > s) || (o.x == s && (base + 0) < t);
      cnt += (o.y > s) || (o.y == s && (base + 1) < t);
      cnt += (o.z > s) || (o.z == s && (base + 2) < t);
      cnt += (o.w > s) || (o.w == s && (base + 3) < t);
    }
    if (cnt < NRETRO) sel[b * NRETRO + cnt] = t;
  }
}

__global__ __launch_bounds__(512) void context_red_k(const float* __restrict__ part,
                                                     float* __restrict__ ctx) {
  int b = blockIdx.x, d = threadIdx.x;
  float s = 0.f;
#pragma unroll
  for (int c = 0; c < 8; ++c) s += part[(size_t)((b << 3) + c) * 512 + d];
  ctx[b * 512 + d] = s * (1.0f / 512.0f);
}

// gather fwd rows -> planes (for q MFMA gemm)
__global__ __launch_bounds__(256) void fwdh_gather_p(const u16* __restrict__ Hh,
                                                     const u16* __restrict__ Hl,
                                                     const int* __restrict__ fwd_idx,
                                                     u16* __restrict__ Fh, u16* __restrict__ Fl) {
  int idx = blockIdx.x * 256 + threadIdx.x;   // 3072*512
  int d = idx & 511, r = idx >> 9;
  int b = r / NFWD, i = r % NFWD;
  int t = fwd_idx[b * NFWD + i];
  int srow = b * 512 + t;
  int si = srow * 512 + (d & ~63) + ((d & 63) ^ ((srow & 7) << 3));
  float v = bf2f(Hh[si]) + bf2f(Hl[si]);
  u16 h = bft(v);
  int di = r * 512 + (d & ~63) + ((d & 63) ^ ((r & 7) << 3));
  Fh[di] = h; Fl[di] = f2bf(v - bf2f(h));
}

// gather retro rows -> memory[48:64] fp32
__global__ __launch_bounds__(256) void retro_gather_p(const u16* __restrict__ Hh,
                                                      const u16* __restrict__ Hl,
                                                      const int* __restrict__ sel,
                                                      float* __restrict__ mem) {
  int idx = blockIdx.x * 256 + threadIdx.x;
  int d = idx & 511, r = idx >> 9, b = r >> 4, j = r & 15;
  int t = sel[b * NRETRO + j];
  int srow = b * 512 + t;
  int si = srow * 512 + (d & ~63) + ((d & 63) ^ ((srow & 7) << 3));
  mem[((size_t)b * 64 + NFWD + j) * 512 + d] = bf2f(Hh[si]) + bf2f(Hl[si]);
}

// S[b,k,t] = q.k / sqrt(512); kk = kvu cols 0-511, stride 1024
__global__ __launch_bounds__(256) void s_k(const float* __restrict__ q,
                                           const u16* __restrict__ kk,
                                           float* __restrict__ S) {
  int b = blockIdx.y, t0 = blockIdx.x * 64;
  int tid = threadIdx.x, tq = tid & 15, kq = tid >> 4;
  __shared__ float qs[16][49];
  __shared__ float ks[16][68];
  float acc[3][4] = {};
  for (int dc = 0; dc < 512; dc += 16) {
    for (int e = tid; e < 768; e += 256) {
      int d = e / 48, k2 = e % 48;
      qs[d][k2] = q[((size_t)b * 48 + k2) * 512 + dc + d];
    }
    for (int e = tid; e < 1024; e += 256) {
      int t = e >> 4, d = e & 15;
      ks[d][t] = bf2f(kk[((size_t)b * 512 + t0 + t) * 1024 + dc + d]);
    }
    __syncthreads();
#pragma unroll
    for (int d = 0; d < 16; ++d) {
      float4 kv = *(const float4*)&ks[d][tq << 2];
#pragma unroll
      for (int j = 0; j < 3; ++j) {
        float qv = qs[d][kq * 3 + j];
        acc[j][0] += qv * kv.x; acc[j][1] += qv * kv.y;
        acc[j][2] += qv * kv.z; acc[j][3] += qv * kv.w;
      }
    }
    __syncthreads();
  }
  const float sc = 0.044194173824159216f;
#pragma unroll
  for (int j = 0; j < 3; ++j) {
    int k = kq * 3 + j;
    float4 o; o.x = acc[j][0] * sc; o.y = acc[j][1] * sc;
    o.z = acc[j][2] * sc; o.w = acc[j][3] * sc;
    *(float4*)&S[((size_t)b * 48 + k) * 512 + t0 + (tq << 2)] = o;
  }
}

__global__ __launch_bounds__(256) void softmax_k(float* __restrict__ S) {
  float* p = S + (size_t)blockIdx.x * 512;
  int tid = threadIdx.x;
  __shared__ float red[256];
  __shared__ float stat[2];
  float v0 = p[tid], v1 = p[tid + 256];
  red[tid] = fmaxf(v0, v1);
  __syncthreads();
  for (int s = 128; s > 0; s >>= 1) { if (tid < s) red[tid] = fmaxf(red[tid], red[tid + s]); __syncthreads(); }
  if (tid == 0) stat[0] = red[0];
  __syncthreads();
  float mx = stat[0];
  float e0 = expf(v0 - mx), e1 = expf(v1 - mx);
  red[tid] = e0 + e1;
  __syncthreads();
  for (int s = 128; s > 0; s >>= 1) { if (tid < s) red[tid] += red[tid + s]; __syncthreads(); }
  if (tid == 0) stat[1] = 1.0f / red[0];
  __syncthreads();
  float inv = stat[1];
  p[tid] = e0 * inv; p[tid + 256] = e1 * inv;
}

// attn_out = P @ V; V = kvu cols 512-1023 (vvp=base+512), stride 1024;
// outputs swizzled hi/lo planes for the wo MFMA gemm
__global__ __launch_bounds__(256) void pv_k(const float* __restrict__ P,
                                            const u16* __restrict__ vvp,
                                            u16* __restrict__ Ph, u16* __restrict__ Pl) {
  int b = blockIdx.y, d0 = blockIdx.x * 64;
  int tid = threadIdx.x, dq = tid & 15, kq = tid >> 4;
  __shared__ float ps[16][49];
  __shared__ float vs[16][68];
  float acc[3][4] = {};
  for (int tc = 0; tc < 512; tc += 16) {
    for (int e = tid; e < 768; e += 256) {
      int t = e / 48, k2 = e % 48;
      ps[t][k2] = P[((size_t)b * 48 + k2) * 512 + tc + t];
    }
    for (int e = tid; e < 1024; e += 256) {
      int t = e >> 6, d = e & 63;
      vs[t][d] = bf2f(vvp[((size_t)b * 512 + tc + t) * 1024 + d0 + d]);
    }
    __syncthreads();
#pragma unroll
    for (int t = 0; t < 16; ++t) {
      float4 vval = *(const float4*)&vs[t][dq << 2];
#pragma unroll
      for (int j = 0; j < 3; ++j) {
        float pp = ps[t][kq * 3 + j];
        acc[j][0] += pp * vval.x; acc[j][1] += pp * vval.y;
        acc[j][2] += pp * vval.z; acc[j][3] += pp * vval.w;
      }
    }
    __syncthreads();
  }
#pragma unroll
  for (int j = 0; j < 3; ++j) {
    int k = kq * 3 + j;
    int row = b * 48 + k;
    int c = (row & 7) << 3;
    int di = row * 512 + d0 + ((dq << 2) ^ c);
    float v0 = acc[j][0], v1 = acc[j][1], v2 = acc[j][2], v3 = acc[j][3];
    u16 h0 = bft(v0), h1 = bft(v1), h2 = bft(v2), h3 = bft(v3);
    uint2 hv, lv;
    hv.x = (u32)h0 | ((u32)h1 << 16); hv.y = (u32)h2 | ((u32)h3 << 16);
    lv.x = (u32)f2bf(v0 - bf2f(h0)) | ((u32)f2bf(v1 - bf2f(h1)) << 16);
    lv.y = (u32)f2bf(v2 - bf2f(h2)) | ((u32)f2bf(v3 - bf2f(h3)) << 16);
    *(uint2*)&Ph[di] = hv;
    *(uint2*)&Pl[di] = lv;
  }
}

__global__ __launch_bounds__(512) void qh_p_k(const u16* __restrict__ Hh,
                                              const u16* __restrict__ Hl,
                                              const float* __restrict__ rq_w,
                                              const float* __restrict__ rq_b,
                                              float* __restrict__ qh) {
  int b = blockIdx.x, d = threadIdx.x;
  __shared__ float hr[512];
  int row = b * 512 + 510;                       // (510&7)=6 -> key 48
  int idx = row * 512 + (d & ~63) + ((d & 63) ^ 48);
  hr[d] = bf2f(Hh[idx]) + bf2f(Hl[idx]);
  __syncthreads();
  float s = 0.f;
  for (int k = 0; k < 512; ++k) s += hr[k] * rq_w[(size_t)k * 512 + d];
  qh[b * 512 + d] = s + rq_b[d];
}

// mem softmax + ctx; emits ctx as swizzled hi/lo planes for out_mgemm
__global__ __launch_bounds__(512) void mem_attn_k(const float* __restrict__ mem,
                                                  const float* __restrict__ qh,
                                                  u16* __restrict__ ctxh,
                                                  u16* __restrict__ ctxl) {
  int b = blockIdx.x, tid = threadIdx.x;
  __shared__ float qv[512];
  __shared__ float sc[64];
  qv[tid] = qh[b * 512 + tid];
  __syncthreads();
  if (tid < 64) {
    const float* mp = mem + ((size_t)b * 64 + tid) * 512;
    float s = 0.f;
    for (int d = 0; d < 512; ++d) s += mp[d] * qv[d];
    float mx = s;
#pragma unroll
    for (int off = 32; off > 0; off >>= 1) mx = fmaxf(mx, __shfl_xor(mx, off));
    float e = expf(s - mx);
    float sum = e;
#pragma unroll
    for (int off = 32; off > 0; off >>= 1) sum += __shfl_xor(sum, off);
    sc[tid] = e / sum;
  }
  __syncthreads();
  float a = 0.f;
  for (int m = 0; m < 64; ++m) a += sc[m] * mem[((size_t)b * 64 + m) * 512 + tid];
  int di = b * 512 + (tid & ~63) + ((tid & 63) ^ ((b & 7) << 3));
  u16 h = bft(a);
  ctxh[di] = h; ctxl[di] = f2bf(a - bf2f(h));
}

extern "C" void kernel_launch(void* const* d_in, const int* in_sizes, int n_in,
                              void* d_out, int out_size, void* d_ws, size_t ws_size,
                              hipStream_t stream) {
  const int*  seq    = (const int*)d_in[0];
  const void* embed  = d_in[1];
  const void* ff_w1  = d_in[2];
  const void* ff_b1  = d_in[3];
  const void* ff_w2  = d_in[4];
  const void* ff_b2  = d_in[5];
  const void* ln_g   = d_in[6];
  const void* ln_b   = d_in[7];
  const void* fg_w   = d_in[8];
  const void* fg_b   = d_in[9];
  const void* nw_w1  = d_in[10];
  const void* nw_b1  = d_in[11];
  const void* nw_w2  = d_in[12];
  const void* nw_b2  = d_in[13];
  const void* wq     = d_in[14];
  const void* bq     = d_in[15];
  const void* wk     = d_in[16];
  const void* bk     = d_in[17];
  const void* wv     = d_in[18];
  const void* bv     = d_in[19];
  const void* wo     = d_in[20];
  const void* bo     = d_in[21];
  const void* rq_w   = d_in[22];
  const void* rq_b   = d_in[23];
  const void* out_w  = d_in[24];
  const void* out_b  = d_in[25];
  float* out = (float*)d_out;

  // ---- workspace (float units), NEED = 43,778,048 f
  float* ws = (float*)d_ws;
  // region A [0, 16,777,216 f): hidden fp32 -> kvu u16[32768][1024]
  float* hidden = ws;
  u16*   kvu    = (u16*)ws;                     // 64 MB
  // region R [16,777,216, 33,554,432 f):
  u16* h0h   = (u16*)(ws + 16777216);           // 8192x512 u16
  u16* h0l   = h0h + 4194304;
  u16* actHh = (u16*)(ws + 20971520);           // 8192x1024 u16
  u16* actHl = actHh + 8388608;
  u16* Hh    = (u16*)(ws + 16777216);           // 32768x512 planes (post-LN)
  u16* Hl    = Hh + 16777216;
  u16* WoT   = (u16*)(ws + 16777216);           // 50304x512 bf16 (over dead H)
  // region S1
  size_t S0 = 33554432;
  float* fwd_scores = ws + S0;
  float* gs         = ws + S0 + 32768;
  float* context    = ws + S0 + 65536;
  float* gate_bias  = ws + S0 + 98304;
  float* qh         = ws + S0 + 131072;
  u16*   ctxh       = (u16*)(ws + S0 + 163840); // ctx hi/lo planes
  u16*   ctxl       = ctxh + 32768;
  int*   fwd_idx    = (int*)(ws + S0 + 196608);
  int*   sel        = (int*)(ws + S0 + 199680);
  int*   fwd_mask   = (int*)(ws + S0 + 200704);
  int*   flagp      = (int*)(ws + S0 + 233472);
  float* bkv        = ws + S0 + 236544;         // 1024 f concat bias
  float* cpart      = ws + S0 + 262144;         // context partials (dies early)
  float* gpart      = ws + S0 + 262144;         // then g1->gs partials [32768][8]
  u16*   Fh         = (u16*)(ws + S0 + 262144); // then fwd_h planes
  u16*   Fl         = Fh + 1572864;
  float* q          = ws + S0 + 1835008;
  float* Smat       = ws + S0 + 3407872;
  // weight planes pack (dead before s_k overwrites as Smat / pv writes Ph)
  u16* W0    = (u16*)(ws + S0 + 3407872);
  u16* WTnh  = W0;            u16* WTnl  = W0 + 262144;
  u16* WTkvh = W0 + 524288;   u16* WTkvl = W0 + 1048576;  // 1024x512 each
  u16* WT1h  = W0 + 1572864;  u16* WT1l  = W0 + 2097152;  // 1024x512 each
  u16* WT2h  = W0 + 2621440;  u16* WT2l  = W0 + 3145728;  // 512x1024 each
  u16* Ph    = (u16*)(ws + S0 + 4980736);       // attn planes (pv out)
  u16* Pl    = Ph + 1572864;
  u16* Wq0   = (u16*)(ws + S0 + 6553600);
  u16* WTqh  = Wq0;          u16* WTql = Wq0 + 262144;
  u16* WToh  = Wq0 + 524288; u16* WTol = Wq0 + 786432;
  float* memory = ws + S0 + 8126464;
  const size_t NEED = (size_t)(33554432 + 10223616) * 4;

  if (ws_size < NEED) {
    float val = 500.0f + (float)(ws_size >> 20);
    sentinel_k<<<(out_size + 255) / 256, 256, 0, stream>>>(out, out_size, val);
    return;
  }

  detect_k<<<1, 1, 0, stream>>>((const u32*)embed, flagp);

  // one-time weight transpose+split (swizzled bf16 planes)
  tsplit_k<<<512, 256, 0, stream>>>((const float*)ff_w1, WT1h, WT1l, 512, 1024);
  tsplit_k<<<512, 256, 0, stream>>>((const float*)ff_w2, WT2h, WT2l, 1024, 512);
  tsplit_k<<<256, 256, 0, stream>>>((const float*)nw_w1, WTnh, WTnl, 512, 512);
  tsplit_k<<<256, 256, 0, stream>>>((const float*)wk, WTkvh, WTkvl, 512, 512);
  tsplit_k<<<256, 256, 0, stream>>>((const float*)wv, WTkvh + 512*512, WTkvl + 512*512, 512, 512);
  tsplit_k<<<256, 256, 0, stream>>>((const float*)wq, WTqh, WTql, 512, 512);
  tsplit_k<<<256, 256, 0, stream>>>((const float*)wo, WToh, WTol, 512, 512);
  concat2_k<<<4, 256, 0, stream>>>((const float*)bk, (const float*)bv, bkv);

  // FFN: 4 M-chunks of 8192; merged N=1024 FFN1 + K=1024 FFN2 per chunk
  for (int mc = 0; mc < 4; ++mc) {
    const int* seqp = seq + mc * 8192;
    float* hid = hidden + (size_t)mc * 8192 * 512;
    gsplit_k<<<2048, 256, 0, stream>>>((const float*)embed, seqp, h0h, h0l);
    mgemm_k<16,8,0,1,2><<<1024, 256, 0, stream>>>(
        h0h, h0l, WT1h, WT1l, 512, 512, 0,
        (const float*)ff_b1, 0, nullptr, nullptr, nullptr,
        nullptr, nullptr,
        nullptr, nullptr, actHh, actHl, 1024);
    mgemm_k<8,16,1,0,0><<<512, 256, 0, stream>>>(
        actHh, actHl, WT2h, WT2l, 1024, 1024, 0,
        (const float*)ff_b2, 0, h0h, h0l, nullptr,
        nullptr, nullptr,
        hid, nullptr, nullptr, nullptr, 512);
  }
  // LayerNorm -> H planes
  ln_split_k<<<32768, 256, 0, stream>>>(hidden, (const float*)ln_g, (const float*)ln_b, Hh, Hl);
  // FUSED fwd gate scores + context partials
  gatectx_k<<<dim3(8,64), 256, 0, stream>>>(Hh, Hl, (const float*)fg_w, (const float*)fg_b,
                                            fwd_scores, cpart);
  topk_fwd_k<<<64, 256, 0, stream>>>(fwd_scores, fwd_idx, fwd_mask);
  context_red_k<<<64, 512, 0, stream>>>(cpart, context);
  // gate_bias = context @ nw_w1[512:,:] + nw_b1 (tiny, SIMT)
  gemm_k<0,0,0,0,0><<<dim3(8,1), 256, 0, stream>>>(
      context, 512, nullptr, nullptr, nw_w1, 512, (size_t)512*512, nw_b1, 0,
      nullptr, nullptr, 0, nullptr, 0, 0, gate_bias, 512, 512, flagp);
  // g1 -> gs FUSED: mgemm computes relu(H@nw_w1 + gb) dotted with nw_w2
  // per-row in-epilogue (no 64MB g1 materialization)
  mgemm_k<8,8,2,1,4><<<2048, 256, 0, stream>>>(
      Hh, Hl, WTnh, WTnl, 512, 512, 0,
      nullptr, 0, nullptr, nullptr, gate_bias,
      (const float*)nw_w2, gpart,
      nullptr, nullptr, nullptr, nullptr, 512);
  gs_red_k<<<128, 256, 0, stream>>>(gpart, (const float*)nw_b2, gs);
  topk_retro_k<<<64, 256, 0, stream>>>(gs, fwd_mask, sel);
  retro_gather_p<<<2048, 256, 0, stream>>>(Hh, Hl, sel, memory);
  // q projection (MFMA, M=3072)
  fwdh_gather_p<<<6144, 256, 0, stream>>>(Hh, Hl, fwd_idx, Fh, Fl);
  mgemm_k<8,8,0,0,0><<<192, 256, 0, stream>>>(
      Fh, Fl, WTqh, WTql, 512, 512, 0,
      (const float*)bq, 0, nullptr, nullptr, nullptr,
      nullptr, nullptr,
      q, nullptr, nullptr, nullptr, 512);
  // K,V fused projection -> kvu[m][1024] bf16 (K cols 0-511, V cols 512-1023)
  mgemm_k<16,8,0,0,1><<<4096, 256, 0, stream>>>(
      Hh, Hl, WTkvh, WTkvl, 512, 512, 0,
      bkv, 0, nullptr, nullptr, nullptr,
      nullptr, nullptr,
      nullptr, kvu, nullptr, nullptr, 1024);
  // attention
  s_k<<<dim3(8,64), 256, 0, stream>>>(q, kvu, Smat);
  softmax_k<<<3072, 256, 0, stream>>>(Smat);
  pv_k<<<dim3(8,64), 256, 0, stream>>>(Smat, kvu + 512, Ph, Pl);
  // re_slots = attn @ wo + bo -> memory[0:48] (OUT=3 row remap)
  mgemm_k<8,8,0,0,3><<<192, 256, 0, stream>>>(
      Ph, Pl, WToh, WTol, 512, 512, 0,
      (const float*)bo, 0, nullptr, nullptr, nullptr,
      nullptr, nullptr,
      memory, nullptr, nullptr, nullptr, 512);
  // qh, memory softmax (-> ctx planes), vocab MFMA projection
  qh_p_k<<<64, 512, 0, stream>>>(Hh, Hl, (const float*)rq_w, (const float*)rq_b, qh);
  mem_attn_k<<<64, 512, 0, stream>>>(memory, qh, ctxh, ctxl);
  tout_k<<<16 * 1572, 256, 0, stream>>>((const float*)out_w, WoT);
  out_mgemm_k<<<393, 256, 0, stream>>>(ctxh, ctxl, WoT, (const float*)out_b, out);
}